// Round 10
// baseline (326.748 us; speedup 1.0000x reference)
//
#include <hip/hip_runtime.h>
#include <math.h>

#define TB  2
#define TT  2048
#define TC  768
#define TH  12
#define TDH 64
#define TI  3072
#define TM  (TB*TT)   // 4096 rows

typedef __attribute__((ext_vector_type(8))) __bf16 bf16x8;
typedef __attribute__((ext_vector_type(4))) __bf16 bf16x4;
typedef __attribute__((ext_vector_type(4))) float  f32x4;

__device__ __forceinline__ float gelu_tanh(float x) {
    float x3 = x * x * x;
    return 0.5f * x * (1.0f + tanhf(0.7978845608028654f * (x + 0.044715f * x3)));
}

// async global->LDS, 16B per lane (wave-uniform LDS base, lane l -> base+l*16)
__device__ __forceinline__ void gld_lds16(const void* g, void* l) {
    __builtin_amdgcn_global_load_lds(
        (const __attribute__((address_space(1))) unsigned int*)g,
        (__attribute__((address_space(3))) unsigned int*)l,
        16, 0, 0);
}

template<int N>
__device__ __forceinline__ void vmcnt_wait() {
    if constexpr (N == 0)      asm volatile("s_waitcnt vmcnt(0)" ::: "memory");
    else if constexpr (N == 2) asm volatile("s_waitcnt vmcnt(2)" ::: "memory");
    else if constexpr (N == 3) asm volatile("s_waitcnt vmcnt(3)" ::: "memory");
    else if constexpr (N == 4) asm volatile("s_waitcnt vmcnt(4)" ::: "memory");
    else if constexpr (N == 6) asm volatile("s_waitcnt vmcnt(6)" ::: "memory");
    else if constexpr (N == 8) asm volatile("s_waitcnt vmcnt(8)" ::: "memory");
    else static_assert(N == 0, "unsupported vmcnt");
}

// ---------------------------------------------------------------------------
// bf16 MFMA GEMM: distance-2 prefetch, templated threads (verified rounds 4-9).
// Round 10: MLP1 -> 256x128 tile, 8 waves as 4x2, wave tile 64x64
// (16 MFMA/wave/iter, 2x round-7 amortization; S=3, LDS 72KB -> 2 blk/CU).
// outproj/MLP2 reverted to measured-best 64x64 / 768-block config.
// ---------------------------------------------------------------------------
#define BK 32

template<int BM_, int BN_, int WM_, int WN_, int THREADS_>
__global__ __launch_bounds__(THREADS_)
void gemm_mfma(const __bf16* __restrict__ A, const __bf16* __restrict__ Bt,
               const float* __restrict__ b0, const float* __restrict__ b1,
               const float* __restrict__ b2, const float* __restrict__ resid,
               float* __restrict__ outf, __bf16* __restrict__ outb,
               int N, int K, size_t wt_stride, size_t out_stride, int ep)
{
    constexpr int WAVES_N = BN_ / WN_;
    constexpr int TMt = WM_ / 16, TNt = WN_ / 16;
    constexpr int RP   = THREADS_ / 4;              // staging rows per pass
    constexpr int AISS = BM_ / RP, BISS = BN_ / RP;
    constexpr int S    = AISS + BISS;               // gld_lds per thread/stage
    constexpr int PASS = THREADS_ * 16;             // bytes per staging pass
    constexpr int TILE = (BM_ + BN_) * BK;          // elems per buffer
    static_assert(AISS >= 1 && BISS >= 1, "tile too small for thread count");
    __shared__ __align__(16) __bf16 lds[3 * TILE];

    const int tid  = threadIdx.x;
    const int wave = tid >> 6, lane = tid & 63;
    const int wm = wave / WAVES_N, wn = wave % WAVES_N;
    const int m0 = blockIdx.y * BM_, n0 = blockIdx.x * BN_;
    const int z  = blockIdx.z;

    const __bf16* Bz = Bt + (size_t)z * wt_stride;
    const size_t Kb = (size_t)K * 2;
    const char* Ag = (const char*)A + (size_t)m0 * Kb;
    const char* Bg = (const char*)Bz + (size_t)n0 * Kb;
    const int srow = tid >> 2;
    const int scol = ((tid & 3) ^ ((tid >> 4) & 3)) * 16;   // swizzled src chunk
    const int wbase = wave * 1024;

    f32x4 acc[TMt][TNt];
    #pragma unroll
    for (int i = 0; i < TMt; ++i)
        #pragma unroll
        for (int j = 0; j < TNt; ++j)
            acc[i][j] = (f32x4){0.f, 0.f, 0.f, 0.f};

    const int arow = wm * WM_ + (lane & 15);
    const int brow = wn * WN_ + (lane & 15);
    const int koff = (((lane >> 4) ^ ((lane >> 2) & 3))) * 8;  // swizzled chunk

    const int nIter = K / BK;

    auto stage = [&](char* base, int k0b) {
        #pragma unroll
        for (int s = 0; s < AISS; ++s)
            gld_lds16(Ag + (size_t)(srow + RP * s) * Kb + k0b + scol,
                      base + s * PASS + wbase);
        char* bbase = base + BM_ * BK * 2;
        #pragma unroll
        for (int s = 0; s < BISS; ++s)
            gld_lds16(Bg + (size_t)(srow + RP * s) * Kb + k0b + scol,
                      bbase + s * PASS + wbase);
    };

    char* P0 = (char*)lds;
    char* P1 = P0 + (size_t)TILE * 2;
    char* P2 = P1 + (size_t)TILE * 2;

    stage(P0, 0);
    if (nIter > 1) stage(P1, BK * 2);
    __builtin_amdgcn_sched_barrier(0);   // pin prologue DMA issue order
    char* cur = P0; char* n1 = P1; char* n2 = P2;

    for (int it = 0; it < nIter; ++it) {
        if (it + 2 < nIter) stage(n2, (it + 2) * (BK * 2));
        __builtin_amdgcn_sched_barrier(0);       // DMA issued before the wait
        const int rem = nIter - 1 - it;          // stages in flight beyond it
        if (rem >= 2)      vmcnt_wait<2 * S>();
        else if (rem == 1) vmcnt_wait<S>();
        else               vmcnt_wait<0>();
        __builtin_amdgcn_s_barrier();            // barrier #1: tile-it ready
        __builtin_amdgcn_sched_barrier(0);

        const __bf16* As = (const __bf16*)cur;
        const __bf16* Bs = As + BM_ * BK;
        bf16x8 af[TMt], bfr[TNt];
        #pragma unroll
        for (int ti = 0; ti < TMt; ++ti)
            af[ti] = *(const bf16x8*)&As[(arow + ti * 16) * BK + koff];
        #pragma unroll
        for (int tj = 0; tj < TNt; ++tj)
            bfr[tj] = *(const bf16x8*)&Bs[(brow + tj * 16) * BK + koff];
        #pragma unroll
        for (int ti = 0; ti < TMt; ++ti)
            #pragma unroll
            for (int tj = 0; tj < TNt; ++tj)
                acc[ti][tj] = __builtin_amdgcn_mfma_f32_16x16x32_bf16(
                    af[ti], bfr[tj], acc[ti][tj], 0, 0, 0);

        __builtin_amdgcn_sched_barrier(0);
        __builtin_amdgcn_s_barrier();            // barrier #2: reads of cur done
        char* t = cur; cur = n1; n1 = n2; n2 = t;
    }

    // C/D: col = lane&15, row = (lane>>4)*4 + r
    const int lrow = m0 + wm * WM_ + ((lane >> 4) << 2);
    const int lcol = n0 + wn * WN_ + (lane & 15);

    if (ep == 0) {
        const float* bias = (z == 0) ? b0 : (z == 1) ? b1 : b2;
        __bf16* outz = outb + (size_t)z * out_stride;
        if (z < 2) {
            #pragma unroll
            for (int tj = 0; tj < TNt; ++tj) {
                int n = lcol + tj * 16;
                float bj = bias[n];
                int h = n >> 6, d = n & 63;
                #pragma unroll
                for (int ti = 0; ti < TMt; ++ti)
                    #pragma unroll
                    for (int r = 0; r < 4; ++r) {
                        int m = lrow + ti * 16 + r;
                        int b = m >> 11, t = m & (TT - 1);
                        outz[((size_t)(b * TH + h) * TT + t) * TDH + d] =
                            (__bf16)(acc[ti][tj][r] + bj);
                    }
            }
        } else {
            #pragma unroll
            for (int tj = 0; tj < TNt; ++tj) {
                int n = lcol + tj * 16;
                float bj = bias[n];
                int h = n >> 6, d = n & 63;
                #pragma unroll
                for (int ti = 0; ti < TMt; ++ti) {
                    int m = lrow + ti * 16;
                    int b = m >> 11, t0 = m & (TT - 1);
                    bf16x4 pk;
                    #pragma unroll
                    for (int r = 0; r < 4; ++r)
                        pk[r] = (__bf16)(acc[ti][tj][r] + bj);
                    *(bf16x4*)(outz + ((size_t)(b * TH + h) * TDH + d) * TT + t0) = pk;
                }
            }
        }
    } else if (ep == 1) {
        #pragma unroll
        for (int tj = 0; tj < TNt; ++tj) {
            int n = lcol + tj * 16;
            float bj = b0[n];
            #pragma unroll
            for (int ti = 0; ti < TMt; ++ti)
                #pragma unroll
                for (int r = 0; r < 4; ++r) {
                    int m = lrow + ti * 16 + r;
                    outf[(size_t)m * N + n] =
                        acc[ti][tj][r] + bj + resid[(size_t)m * N + n];
                }
        }
    } else {
        #pragma unroll
        for (int tj = 0; tj < TNt; ++tj) {
            int n = lcol + tj * 16;
            float bj = b0[n];
            #pragma unroll
            for (int ti = 0; ti < TMt; ++ti)
                #pragma unroll
                for (int r = 0; r < 4; ++r) {
                    int m = lrow + ti * 16 + r;
                    outb[(size_t)m * N + n] = (__bf16)gelu_tanh(acc[ti][tj][r] + bj);
                }
        }
    }
}

// ---------------------------------------------------------------------------
// Fused prep: x fp32->bf16 (blocks [0,1536)) + 6 weight transposes to bf16
// ---------------------------------------------------------------------------
__global__ __launch_bounds__(256)
void prep_kernel(const float* __restrict__ x,
                 const float* __restrict__ Wq, const float* __restrict__ Wk,
                 const float* __restrict__ Wv, const float* __restrict__ Wo,
                 const float* __restrict__ W1, const float* __restrict__ W2,
                 __bf16* __restrict__ x_bf, __bf16* __restrict__ WqkvT,
                 __bf16* __restrict__ WoT, __bf16* __restrict__ W1T,
                 __bf16* __restrict__ W2T)
{
    const size_t WSZ = (size_t)TC * TC;
    int bid = blockIdx.x;
    if (bid < 1536) {                        // x conversion: 1536*256*8 = MC
        int i = (bid * 256 + threadIdx.x) * 8;
        float4 a = *(const float4*)(x + i);
        float4 b = *(const float4*)(x + i + 4);
        bf16x8 v;
        v[0] = (__bf16)a.x; v[1] = (__bf16)a.y; v[2] = (__bf16)a.z; v[3] = (__bf16)a.w;
        v[4] = (__bf16)b.x; v[5] = (__bf16)b.y; v[6] = (__bf16)b.z; v[7] = (__bf16)b.w;
        *(bf16x8*)(x_bf + i) = v;
        return;
    }
    bid -= 1536;
    const float* src; __bf16* dst; int K, N, tloc;
    if (bid < 2304) {            // Wq/Wk/Wv/Wo: 576 tiles each
        int w = bid / 576; tloc = bid - w * 576;
        K = TC; N = TC;
        src = (w == 0) ? Wq : (w == 1) ? Wk : (w == 2) ? Wv : Wo;
        dst = (w < 3) ? (WqkvT + (size_t)w * WSZ) : WoT;
    } else if (bid < 4608) {     // W1 [768,3072]
        tloc = bid - 2304; K = TC; N = TI; src = W1; dst = W1T;
    } else {                     // W2 [3072,768]
        tloc = bid - 4608; K = TI; N = TC; src = W2; dst = W2T;
    }
    int tiles_x = N >> 5;
    int n0 = (tloc % tiles_x) * 32, k0 = (tloc / tiles_x) * 32;

    __shared__ float tile[32][33];
    const int tx = threadIdx.x & 31, ty = threadIdx.x >> 5;
    #pragma unroll
    for (int i = 0; i < 32; i += 8)
        tile[ty + i][tx] = src[(size_t)(k0 + ty + i) * N + n0 + tx];
    __syncthreads();
    #pragma unroll
    for (int i = 0; i < 32; i += 8)
        dst[(size_t)(n0 + ty + i) * K + k0 + tx] = (__bf16)tile[tx][ty + i];
}

// ---------------------------------------------------------------------------
// LayerNorm (ddof=1, EPS=1e-4), optional bf16 copy
// ---------------------------------------------------------------------------
__global__ __launch_bounds__(256)
void ln_kernel(const float* __restrict__ in, const float* __restrict__ gs,
               const float* __restrict__ gb, float* __restrict__ out,
               __bf16* __restrict__ out_bf)
{
    const int row = blockIdx.x, tid = threadIdx.x;
    const float* r = in + (size_t)row * TC;
    float x0 = r[tid], x1 = r[tid + 256], x2 = r[tid + 512];
    float s = x0 + x1 + x2;
    float q = x0 * x0 + x1 * x1 + x2 * x2;
    #pragma unroll
    for (int off = 32; off > 0; off >>= 1) {
        s += __shfl_down(s, off);
        q += __shfl_down(q, off);
    }
    __shared__ float partial[8];
    __shared__ float stats[2];
    int wid = tid >> 6, lane = tid & 63;
    if (lane == 0) { partial[wid] = s; partial[wid + 4] = q; }
    __syncthreads();
    if (tid == 0) {
        float S = partial[0] + partial[1] + partial[2] + partial[3];
        float Q = partial[4] + partial[5] + partial[6] + partial[7];
        float mean = S * (1.0f / (float)TC);
        float var = (Q - (float)TC * mean * mean) * (1.0f / (float)(TC - 1));
        stats[0] = mean;
        stats[1] = rsqrtf(var + 1e-4f);
    }
    __syncthreads();
    float mean = stats[0], rstd = stats[1];
    float* w = out + (size_t)row * TC;
    float y0 = gs[tid]       * ((x0 - mean) * rstd) + gb[tid];
    float y1 = gs[tid + 256] * ((x1 - mean) * rstd) + gb[tid + 256];
    float y2 = gs[tid + 512] * ((x2 - mean) * rstd) + gb[tid + 512];
    w[tid] = y0; w[tid + 256] = y1; w[tid + 512] = y2;
    if (out_bf) {
        __bf16* wb = out_bf + (size_t)row * TC;
        wb[tid] = (__bf16)y0; wb[tid + 256] = (__bf16)y1; wb[tid + 512] = (__bf16)y2;
    }
}

// ---------------------------------------------------------------------------
// MFMA flash attention v4 (round-6/9 version, best measured 62.5 us):
// 768-block snake, 3 blocks/CU, KVBLK=128 per iter, defer-max, exp2 softmax.
// ---------------------------------------------------------------------------
#define AP 72
#define VP 136
#define ATT_SCALE 0.18033688011112042f   /* 0.125 * log2(e) */

__global__ __launch_bounds__(256)
void attn_mfma(const __bf16* __restrict__ Q, const __bf16* __restrict__ K,
               const __bf16* __restrict__ Vt, __bf16* __restrict__ ctx)
{
    __shared__ __align__(16) __bf16 Ks[128 * AP];
    __shared__ __align__(16) __bf16 Vs[64 * VP];
    __shared__ __align__(16) __bf16 Ps[64 * VP];

    const int tid  = threadIdx.x;
    const int wave = tid >> 6, lane = tid & 63;
    const int c = lane & 15, g = lane >> 4;
    const int bh = blockIdx.y;
    const int qi = blockIdx.x;
    const int qt = (qi & 1) ? (31 - (qi >> 1)) : (qi >> 1);
    const int q_glob = qt * 64 + wave * 16 + c;

    const __bf16* Qb = Q  + (size_t)bh * TT * TDH;
    const __bf16* Kb = K  + (size_t)bh * TT * TDH;
    const __bf16* Vb = Vt + (size_t)bh * TDH * TT;

    bf16x8 qf0 = *(const bf16x8*)(Qb + (size_t)q_glob * TDH + g * 8);
    bf16x8 qf1 = *(const bf16x8*)(Qb + (size_t)q_glob * TDH + 32 + g * 8);

    const int krow = tid >> 3, kcol = (tid & 7) * 8;
    const int vrow = tid >> 4, vcol = (tid & 15) * 8;

    float m_i = -1e30f, l_i = 0.0f;
    f32x4 acc[4];
    #pragma unroll
    for (int m2 = 0; m2 < 4; ++m2) acc[m2] = (f32x4){0.f, 0.f, 0.f, 0.f};

    const int pmax = qt >> 1;
    for (int p = 0; p <= pmax; ++p) {
        const int kb = p * 128;
        bf16x8 kv[4], vv[4];
        #pragma unroll
        for (int s = 0; s < 4; ++s) {
            kv[s] = *(const bf16x8*)(Kb + (size_t)(kb + krow + 32 * s) * TDH + kcol);
            vv[s] = *(const bf16x8*)(Vb + (size_t)(vrow + 16 * s) * TT + kb + vcol);
        }
        __syncthreads();
        #pragma unroll
        for (int s = 0; s < 4; ++s) {
            *(bf16x8*)&Ks[(krow + 32 * s) * AP + kcol] = kv[s];
            *(bf16x8*)&Vs[(vrow + 16 * s) * VP + vcol] = vv[s];
        }
        __syncthreads();

        f32x4 st[8];
        #pragma unroll
        for (int g2 = 0; g2 < 8; ++g2) {
            bf16x8 af0 = *(const bf16x8*)&Ks[(16 * g2 + c) * AP + g * 8];
            bf16x8 af1 = *(const bf16x8*)&Ks[(16 * g2 + c) * AP + 32 + g * 8];
            f32x4 z = (f32x4){0.f, 0.f, 0.f, 0.f};
            z = __builtin_amdgcn_mfma_f32_16x16x32_bf16(af0, qf0, z, 0, 0, 0);
            z = __builtin_amdgcn_mfma_f32_16x16x32_bf16(af1, qf1, z, 0, 0, 0);
            st[g2] = z;
        }

        float sv[8][4];
        float mx = -1e30f;
        if (p == pmax) {            // diagonal pair: causal mask
            #pragma unroll
            for (int g2 = 0; g2 < 8; ++g2)
                #pragma unroll
                for (int r = 0; r < 4; ++r) {
                    int kcol2 = kb + 16 * g2 + 4 * g + r;
                    float v = (kcol2 > q_glob) ? -1e30f : st[g2][r] * ATT_SCALE;
                    sv[g2][r] = v;
                    mx = fmaxf(mx, v);
                }
        } else {
            #pragma unroll
            for (int g2 = 0; g2 < 8; ++g2)
                #pragma unroll
                for (int r = 0; r < 4; ++r) {
                    float v = st[g2][r] * ATT_SCALE;
                    sv[g2][r] = v;
                    mx = fmaxf(mx, v);
                }
        }
        mx = fmaxf(mx, __shfl_xor(mx, 16));
        mx = fmaxf(mx, __shfl_xor(mx, 32));

        float nm = m_i;
        if (!__all(mx <= m_i + 8.0f)) {
            nm = fmaxf(m_i, mx);
            float corr = exp2f(m_i - nm);
            l_i *= corr;
            #pragma unroll
            for (int m2 = 0; m2 < 4; ++m2) {
                acc[m2][0] *= corr; acc[m2][1] *= corr;
                acc[m2][2] *= corr; acc[m2][3] *= corr;
            }
            m_i = nm;
        }

        float ps = 0.f;
        #pragma unroll
        for (int g2 = 0; g2 < 8; ++g2) {
            bf16x4 pk;
            #pragma unroll
            for (int r = 0; r < 4; ++r) {
                float pp = exp2f(sv[g2][r] - nm);
                ps += pp;
                pk[r] = (__bf16)pp;
            }
            *(bf16x4*)&Ps[(wave * 16 + c) * VP + 16 * g2 + 4 * g] = pk;
        }
        ps += __shfl_xor(ps, 16);
        ps += __shfl_xor(ps, 32);
        l_i += ps;

        bf16x8 pf[4];
        #pragma unroll
        for (int s = 0; s < 4; ++s)
            pf[s] = *(const bf16x8*)&Ps[(wave * 16 + c) * VP + 32 * s + g * 8];
        #pragma unroll
        for (int m2 = 0; m2 < 4; ++m2) {
            #pragma unroll
            for (int s = 0; s < 4; ++s) {
                bf16x8 vf = *(const bf16x8*)&Vs[(16 * m2 + c) * VP + 32 * s + g * 8];
                acc[m2] = __builtin_amdgcn_mfma_f32_16x16x32_bf16(vf, pf[s], acc[m2], 0, 0, 0);
            }
        }
    }

    const int b = bh / TH, h = bh - b * TH;
    float inv = 1.0f / l_i;
    #pragma unroll
    for (int m2 = 0; m2 < 4; ++m2) {
        bf16x4 o;
        #pragma unroll
        for (int r = 0; r < 4; ++r)
            o[r] = (__bf16)(acc[m2][r] * inv);
        *(bf16x4*)(ctx + ((size_t)b * TT + q_glob) * TC + h * TDH + 16 * m2 + 4 * g) = o;
    }
}

// ---------------------------------------------------------------------------
extern "C" void kernel_launch(void* const* d_in, const int* in_sizes, int n_in,
                              void* d_out, int out_size, void* d_ws, size_t ws_size,
                              hipStream_t stream)
{
    const float* x    = (const float*)d_in[0];
    const float* Wq   = (const float*)d_in[1];
    const float* bq   = (const float*)d_in[2];
    const float* Wk   = (const float*)d_in[3];
    const float* bk   = (const float*)d_in[4];
    const float* Wv   = (const float*)d_in[5];
    const float* bv   = (const float*)d_in[6];
    const float* Wo   = (const float*)d_in[7];
    const float* bo   = (const float*)d_in[8];
    const float* ln1s = (const float*)d_in[9];
    const float* ln1b = (const float*)d_in[10];
    const float* W1   = (const float*)d_in[11];
    const float* b1   = (const float*)d_in[12];
    const float* W2   = (const float*)d_in[13];
    const float* b2   = (const float*)d_in[14];
    const float* ln2s = (const float*)d_in[15];
    const float* ln2b = (const float*)d_in[16];
    float* out = (float*)d_out;

    const size_t MC  = (size_t)TM * TC;       // 3,145,728 elems
    const size_t MCB = MC * 2;                // bytes of one bf16 [TM,TC]
    const size_t WSZ = (size_t)TC * TC;
    const size_t W12 = (size_t)TC * TI;

    char* W = (char*)d_ws;
    __bf16* qkvb  = (__bf16*)W;
    __bf16* x_bf  = (__bf16*)(W + 3 * MCB);
    float*  tmp1  = (float*)W;
    __bf16* u_bf  = (__bf16*)W;
    float*  h_f32 = (float*)(W + 4 * MCB);
    __bf16* ctxh  = (__bf16*)(W + 6 * MCB);
    __bf16* wts   = (__bf16*)(W + 7 * MCB);
    __bf16* WqkvT = wts;
    __bf16* WoT   = WqkvT + 3 * WSZ;
    __bf16* W1T   = WoT + WSZ;
    __bf16* W2T   = W1T + W12;

    prep_kernel<<<dim3(1536 + 6912), dim3(256), 0, stream>>>(
        x, Wq, Wk, Wv, Wo, W1, W2, x_bf, WqkvT, WoT, W1T, W2T);

    // QKV: 128x128 tiles, 512 thr / 8 waves, grid 6x32x3 = 576 blocks
    gemm_mfma<128, 128, 64, 32, 512><<<dim3(TC / 128, TM / 128, 3), dim3(512), 0, stream>>>(
        x_bf, WqkvT, bq, bk, bv, nullptr, nullptr, qkvb, TC, TC, WSZ, MC, 0);

    attn_mfma<<<dim3(TT / 64, TB * TH), dim3(256), 0, stream>>>(
        qkvb, qkvb + MC, qkvb + 2 * MC, ctxh);

    // out-proj + residual(x): 64x64 tiles (measured best), grid 12x64 = 768
    gemm_mfma<64, 64, 32, 32, 256><<<dim3(TC / 64, TM / 64, 1), dim3(256), 0, stream>>>(
        ctxh, WoT, bo, nullptr, nullptr, x, tmp1, nullptr, TC, TC, 0, 0, 1);

    ln_kernel<<<dim3(TM), dim3(256), 0, stream>>>(tmp1, ln1s, ln1b, h_f32, ctxh);

    // MLP1 + gelu: 256x128 tiles, 512 thr / 8 waves (wave 64x64, 16 MFMA/iter),
    // grid 24x16 = 384 blocks, LDS 72KB -> 2 blocks/CU
    gemm_mfma<256, 128, 64, 64, 512><<<dim3(TI / 128, TM / 256, 1), dim3(512), 0, stream>>>(
        ctxh, W1T, b1, nullptr, nullptr, nullptr, nullptr, u_bf, TI, TC, 0, 0, 2);

    // MLP2 + residual(h): 64x64 tiles (measured best), grid 12x64 = 768
    gemm_mfma<64, 64, 32, 32, 256><<<dim3(TC / 64, TM / 64, 1), dim3(256), 0, stream>>>(
        u_bf, W2T, b2, nullptr, nullptr, h_f32, out, nullptr, TC, TI, 0, 0, 1);

    ln_kernel<<<dim3(TM), dim3(256), 0, stream>>>(out, ln2s, ln2b, out, nullptr);
}

// Round 11
// 315.604 us; speedup vs baseline: 1.0353x; 1.0353x over previous
//
#include <hip/hip_runtime.h>
#include <math.h>

#define TB  2
#define TT  2048
#define TC  768
#define TH  12
#define TDH 64
#define TI  3072
#define TM  (TB*TT)   // 4096 rows

typedef __attribute__((ext_vector_type(8))) __bf16 bf16x8;
typedef __attribute__((ext_vector_type(4))) __bf16 bf16x4;
typedef __attribute__((ext_vector_type(4))) float  f32x4;

__device__ __forceinline__ float gelu_tanh(float x) {
    float x3 = x * x * x;
    return 0.5f * x * (1.0f + tanhf(0.7978845608028654f * (x + 0.044715f * x3)));
}

// async global->LDS, 16B per lane (wave-uniform LDS base, lane l -> base+l*16)
__device__ __forceinline__ void gld_lds16(const void* g, void* l) {
    __builtin_amdgcn_global_load_lds(
        (const __attribute__((address_space(1))) unsigned int*)g,
        (__attribute__((address_space(3))) unsigned int*)l,
        16, 0, 0);
}

template<int N>
__device__ __forceinline__ void vmcnt_wait() {
    if constexpr (N == 0)      asm volatile("s_waitcnt vmcnt(0)" ::: "memory");
    else if constexpr (N == 2) asm volatile("s_waitcnt vmcnt(2)" ::: "memory");
    else if constexpr (N == 3) asm volatile("s_waitcnt vmcnt(3)" ::: "memory");
    else if constexpr (N == 4) asm volatile("s_waitcnt vmcnt(4)" ::: "memory");
    else if constexpr (N == 6) asm volatile("s_waitcnt vmcnt(6)" ::: "memory");
    else if constexpr (N == 8) asm volatile("s_waitcnt vmcnt(8)" ::: "memory");
    else static_assert(N == 0, "unsupported vmcnt");
}

// ---------------------------------------------------------------------------
// bf16 MFMA GEMM: distance-2 prefetch, templated threads (verified rounds 4-10).
// Round 11: round-7 configuration (measured best, 312.0 us) + SPLIT-K for
// MLP2 (K=3072 -> 2 halves of 1536; serial K-chain 96 -> 48 iters, blocks
// 768 -> 1536 = 6/CU). New params: Krow (full-K row stride; K = loop extent),
// a_zoff (per-z byte offset into A's k dim). ep=3: atomicAdd partial into
// outf (out pre-initialized to h + b2 by ln1 -> no resid read, no bias).
// ---------------------------------------------------------------------------
#define BK 32

template<int BM_, int BN_, int WM_, int WN_, int THREADS_>
__global__ __launch_bounds__(THREADS_)
void gemm_mfma(const __bf16* __restrict__ A, const __bf16* __restrict__ Bt,
               const float* __restrict__ b0, const float* __restrict__ b1,
               const float* __restrict__ b2, const float* __restrict__ resid,
               float* __restrict__ outf, __bf16* __restrict__ outb,
               int N, int K, int Krow, size_t wt_stride, size_t a_zoff,
               size_t out_stride, int ep)
{
    constexpr int WAVES_N = BN_ / WN_;
    constexpr int TMt = WM_ / 16, TNt = WN_ / 16;
    constexpr int RP   = THREADS_ / 4;              // staging rows per pass
    constexpr int AISS = BM_ / RP, BISS = BN_ / RP;
    constexpr int S    = AISS + BISS;               // gld_lds per thread/stage
    constexpr int PASS = THREADS_ * 16;             // bytes per staging pass
    constexpr int TILE = (BM_ + BN_) * BK;          // elems per buffer
    static_assert(AISS >= 1 && BISS >= 1, "tile too small for thread count");
    __shared__ __align__(16) __bf16 lds[3 * TILE];

    const int tid  = threadIdx.x;
    const int wave = tid >> 6, lane = tid & 63;
    const int wm = wave / WAVES_N, wn = wave % WAVES_N;
    const int m0 = blockIdx.y * BM_, n0 = blockIdx.x * BN_;
    const int z  = blockIdx.z;

    const __bf16* Bz = Bt + (size_t)z * wt_stride;
    const size_t Kb = (size_t)Krow * 2;             // row stride (bytes)
    const char* Ag = (const char*)A + (size_t)m0 * Kb + (size_t)z * a_zoff;
    const char* Bg = (const char*)Bz + (size_t)n0 * Kb;
    const int srow = tid >> 2;
    const int scol = ((tid & 3) ^ ((tid >> 4) & 3)) * 16;   // swizzled src chunk
    const int wbase = wave * 1024;

    f32x4 acc[TMt][TNt];
    #pragma unroll
    for (int i = 0; i < TMt; ++i)
        #pragma unroll
        for (int j = 0; j < TNt; ++j)
            acc[i][j] = (f32x4){0.f, 0.f, 0.f, 0.f};

    const int arow = wm * WM_ + (lane & 15);
    const int brow = wn * WN_ + (lane & 15);
    const int koff = (((lane >> 4) ^ ((lane >> 2) & 3))) * 8;  // swizzled chunk

    const int nIter = K / BK;

    auto stage = [&](char* base, int k0b) {
        #pragma unroll
        for (int s = 0; s < AISS; ++s)
            gld_lds16(Ag + (size_t)(srow + RP * s) * Kb + k0b + scol,
                      base + s * PASS + wbase);
        char* bbase = base + BM_ * BK * 2;
        #pragma unroll
        for (int s = 0; s < BISS; ++s)
            gld_lds16(Bg + (size_t)(srow + RP * s) * Kb + k0b + scol,
                      bbase + s * PASS + wbase);
    };

    char* P0 = (char*)lds;
    char* P1 = P0 + (size_t)TILE * 2;
    char* P2 = P1 + (size_t)TILE * 2;

    stage(P0, 0);
    if (nIter > 1) stage(P1, BK * 2);
    __builtin_amdgcn_sched_barrier(0);   // pin prologue DMA issue order
    char* cur = P0; char* n1 = P1; char* n2 = P2;

    for (int it = 0; it < nIter; ++it) {
        if (it + 2 < nIter) stage(n2, (it + 2) * (BK * 2));
        __builtin_amdgcn_sched_barrier(0);       // DMA issued before the wait
        const int rem = nIter - 1 - it;          // stages in flight beyond it
        if (rem >= 2)      vmcnt_wait<2 * S>();
        else if (rem == 1) vmcnt_wait<S>();
        else               vmcnt_wait<0>();
        __builtin_amdgcn_s_barrier();            // barrier #1: tile-it ready
        __builtin_amdgcn_sched_barrier(0);

        const __bf16* As = (const __bf16*)cur;
        const __bf16* Bs = As + BM_ * BK;
        bf16x8 af[TMt], bfr[TNt];
        #pragma unroll
        for (int ti = 0; ti < TMt; ++ti)
            af[ti] = *(const bf16x8*)&As[(arow + ti * 16) * BK + koff];
        #pragma unroll
        for (int tj = 0; tj < TNt; ++tj)
            bfr[tj] = *(const bf16x8*)&Bs[(brow + tj * 16) * BK + koff];
        #pragma unroll
        for (int ti = 0; ti < TMt; ++ti)
            #pragma unroll
            for (int tj = 0; tj < TNt; ++tj)
                acc[ti][tj] = __builtin_amdgcn_mfma_f32_16x16x32_bf16(
                    af[ti], bfr[tj], acc[ti][tj], 0, 0, 0);

        __builtin_amdgcn_sched_barrier(0);
        __builtin_amdgcn_s_barrier();            // barrier #2: reads of cur done
        char* t = cur; cur = n1; n1 = n2; n2 = t;
    }

    // C/D: col = lane&15, row = (lane>>4)*4 + r
    const int lrow = m0 + wm * WM_ + ((lane >> 4) << 2);
    const int lcol = n0 + wn * WN_ + (lane & 15);

    if (ep == 0) {
        const float* bias = (z == 0) ? b0 : (z == 1) ? b1 : b2;
        __bf16* outz = outb + (size_t)z * out_stride;
        if (z < 2) {
            #pragma unroll
            for (int tj = 0; tj < TNt; ++tj) {
                int n = lcol + tj * 16;
                float bj = bias[n];
                int h = n >> 6, d = n & 63;
                #pragma unroll
                for (int ti = 0; ti < TMt; ++ti)
                    #pragma unroll
                    for (int r = 0; r < 4; ++r) {
                        int m = lrow + ti * 16 + r;
                        int b = m >> 11, t = m & (TT - 1);
                        outz[((size_t)(b * TH + h) * TT + t) * TDH + d] =
                            (__bf16)(acc[ti][tj][r] + bj);
                    }
            }
        } else {
            #pragma unroll
            for (int tj = 0; tj < TNt; ++tj) {
                int n = lcol + tj * 16;
                float bj = bias[n];
                int h = n >> 6, d = n & 63;
                #pragma unroll
                for (int ti = 0; ti < TMt; ++ti) {
                    int m = lrow + ti * 16;
                    int b = m >> 11, t0 = m & (TT - 1);
                    bf16x4 pk;
                    #pragma unroll
                    for (int r = 0; r < 4; ++r)
                        pk[r] = (__bf16)(acc[ti][tj][r] + bj);
                    *(bf16x4*)(outz + ((size_t)(b * TH + h) * TDH + d) * TT + t0) = pk;
                }
            }
        }
    } else if (ep == 1) {
        #pragma unroll
        for (int tj = 0; tj < TNt; ++tj) {
            int n = lcol + tj * 16;
            float bj = b0[n];
            #pragma unroll
            for (int ti = 0; ti < TMt; ++ti)
                #pragma unroll
                for (int r = 0; r < 4; ++r) {
                    int m = lrow + ti * 16 + r;
                    outf[(size_t)m * N + n] =
                        acc[ti][tj][r] + bj + resid[(size_t)m * N + n];
                }
        }
    } else if (ep == 2) {
        #pragma unroll
        for (int tj = 0; tj < TNt; ++tj) {
            int n = lcol + tj * 16;
            float bj = b0[n];
            #pragma unroll
            for (int ti = 0; ti < TMt; ++ti)
                #pragma unroll
                for (int r = 0; r < 4; ++r) {
                    int m = lrow + ti * 16 + r;
                    outb[(size_t)m * N + n] = (__bf16)gelu_tanh(acc[ti][tj][r] + bj);
                }
        }
    } else {   // ep == 3: split-K partial -> atomic accumulate (out pre-inited)
        #pragma unroll
        for (int tj = 0; tj < TNt; ++tj) {
            int n = lcol + tj * 16;
            #pragma unroll
            for (int ti = 0; ti < TMt; ++ti)
                #pragma unroll
                for (int r = 0; r < 4; ++r) {
                    int m = lrow + ti * 16 + r;
                    atomicAdd(&outf[(size_t)m * N + n], acc[ti][tj][r]);
                }
        }
    }
}

// ---------------------------------------------------------------------------
// Fused prep: x fp32->bf16 (blocks [0,1536)) + 6 weight transposes to bf16
// ---------------------------------------------------------------------------
__global__ __launch_bounds__(256)
void prep_kernel(const float* __restrict__ x,
                 const float* __restrict__ Wq, const float* __restrict__ Wk,
                 const float* __restrict__ Wv, const float* __restrict__ Wo,
                 const float* __restrict__ W1, const float* __restrict__ W2,
                 __bf16* __restrict__ x_bf, __bf16* __restrict__ WqkvT,
                 __bf16* __restrict__ WoT, __bf16* __restrict__ W1T,
                 __bf16* __restrict__ W2T)
{
    const size_t WSZ = (size_t)TC * TC;
    int bid = blockIdx.x;
    if (bid < 1536) {                        // x conversion: 1536*256*8 = MC
        int i = (bid * 256 + threadIdx.x) * 8;
        float4 a = *(const float4*)(x + i);
        float4 b = *(const float4*)(x + i + 4);
        bf16x8 v;
        v[0] = (__bf16)a.x; v[1] = (__bf16)a.y; v[2] = (__bf16)a.z; v[3] = (__bf16)a.w;
        v[4] = (__bf16)b.x; v[5] = (__bf16)b.y; v[6] = (__bf16)b.z; v[7] = (__bf16)b.w;
        *(bf16x8*)(x_bf + i) = v;
        return;
    }
    bid -= 1536;
    const float* src; __bf16* dst; int K, N, tloc;
    if (bid < 2304) {            // Wq/Wk/Wv/Wo: 576 tiles each
        int w = bid / 576; tloc = bid - w * 576;
        K = TC; N = TC;
        src = (w == 0) ? Wq : (w == 1) ? Wk : (w == 2) ? Wv : Wo;
        dst = (w < 3) ? (WqkvT + (size_t)w * WSZ) : WoT;
    } else if (bid < 4608) {     // W1 [768,3072]
        tloc = bid - 2304; K = TC; N = TI; src = W1; dst = W1T;
    } else {                     // W2 [3072,768]
        tloc = bid - 4608; K = TI; N = TC; src = W2; dst = W2T;
    }
    int tiles_x = N >> 5;
    int n0 = (tloc % tiles_x) * 32, k0 = (tloc / tiles_x) * 32;

    __shared__ float tile[32][33];
    const int tx = threadIdx.x & 31, ty = threadIdx.x >> 5;
    #pragma unroll
    for (int i = 0; i < 32; i += 8)
        tile[ty + i][tx] = src[(size_t)(k0 + ty + i) * N + n0 + tx];
    __syncthreads();
    #pragma unroll
    for (int i = 0; i < 32; i += 8)
        dst[(size_t)(n0 + ty + i) * K + k0 + tx] = (__bf16)tile[tx][ty + i];
}

// ---------------------------------------------------------------------------
// LayerNorm (ddof=1, EPS=1e-4); optional f32 out, optional bf16 out,
// optional "init" output: io[row][c] = y[c] + ib[c]  (pre-init for split-K).
// ---------------------------------------------------------------------------
__global__ __launch_bounds__(256)
void ln_kernel(const float* __restrict__ in, const float* __restrict__ gs,
               const float* __restrict__ gb, float* __restrict__ out,
               __bf16* __restrict__ out_bf,
               const float* __restrict__ ib, float* __restrict__ io)
{
    const int row = blockIdx.x, tid = threadIdx.x;
    const float* r = in + (size_t)row * TC;
    float x0 = r[tid], x1 = r[tid + 256], x2 = r[tid + 512];
    float s = x0 + x1 + x2;
    float q = x0 * x0 + x1 * x1 + x2 * x2;
    #pragma unroll
    for (int off = 32; off > 0; off >>= 1) {
        s += __shfl_down(s, off);
        q += __shfl_down(q, off);
    }
    __shared__ float partial[8];
    __shared__ float stats[2];
    int wid = tid >> 6, lane = tid & 63;
    if (lane == 0) { partial[wid] = s; partial[wid + 4] = q; }
    __syncthreads();
    if (tid == 0) {
        float S = partial[0] + partial[1] + partial[2] + partial[3];
        float Q = partial[4] + partial[5] + partial[6] + partial[7];
        float mean = S * (1.0f / (float)TC);
        float var = (Q - (float)TC * mean * mean) * (1.0f / (float)(TC - 1));
        stats[0] = mean;
        stats[1] = rsqrtf(var + 1e-4f);
    }
    __syncthreads();
    float mean = stats[0], rstd = stats[1];
    float y0 = gs[tid]       * ((x0 - mean) * rstd) + gb[tid];
    float y1 = gs[tid + 256] * ((x1 - mean) * rstd) + gb[tid + 256];
    float y2 = gs[tid + 512] * ((x2 - mean) * rstd) + gb[tid + 512];
    if (out) {
        float* w = out + (size_t)row * TC;
        w[tid] = y0; w[tid + 256] = y1; w[tid + 512] = y2;
    }
    if (out_bf) {
        __bf16* wb = out_bf + (size_t)row * TC;
        wb[tid] = (__bf16)y0; wb[tid + 256] = (__bf16)y1; wb[tid + 512] = (__bf16)y2;
    }
    if (io) {
        float* w2 = io + (size_t)row * TC;
        w2[tid]       = y0 + ib[tid];
        w2[tid + 256] = y1 + ib[tid + 256];
        w2[tid + 512] = y2 + ib[tid + 512];
    }
}

// ---------------------------------------------------------------------------
// MFMA flash attention v4 (round-6/9 version, best measured 62.5 us):
// 768-block snake, 3 blocks/CU, KVBLK=128 per iter, defer-max, exp2 softmax.
// ---------------------------------------------------------------------------
#define AP 72
#define VP 136
#define ATT_SCALE 0.18033688011112042f   /* 0.125 * log2(e) */

__global__ __launch_bounds__(256)
void attn_mfma(const __bf16* __restrict__ Q, const __bf16* __restrict__ K,
               const __bf16* __restrict__ Vt, __bf16* __restrict__ ctx)
{
    __shared__ __align__(16) __bf16 Ks[128 * AP];
    __shared__ __align__(16) __bf16 Vs[64 * VP];
    __shared__ __align__(16) __bf16 Ps[64 * VP];

    const int tid  = threadIdx.x;
    const int wave = tid >> 6, lane = tid & 63;
    const int c = lane & 15, g = lane >> 4;
    const int bh = blockIdx.y;
    const int qi = blockIdx.x;
    const int qt = (qi & 1) ? (31 - (qi >> 1)) : (qi >> 1);
    const int q_glob = qt * 64 + wave * 16 + c;

    const __bf16* Qb = Q  + (size_t)bh * TT * TDH;
    const __bf16* Kb = K  + (size_t)bh * TT * TDH;
    const __bf16* Vb = Vt + (size_t)bh * TDH * TT;

    bf16x8 qf0 = *(const bf16x8*)(Qb + (size_t)q_glob * TDH + g * 8);
    bf16x8 qf1 = *(const bf16x8*)(Qb + (size_t)q_glob * TDH + 32 + g * 8);

    const int krow = tid >> 3, kcol = (tid & 7) * 8;
    const int vrow = tid >> 4, vcol = (tid & 15) * 8;

    float m_i = -1e30f, l_i = 0.0f;
    f32x4 acc[4];
    #pragma unroll
    for (int m2 = 0; m2 < 4; ++m2) acc[m2] = (f32x4){0.f, 0.f, 0.f, 0.f};

    const int pmax = qt >> 1;
    for (int p = 0; p <= pmax; ++p) {
        const int kb = p * 128;
        bf16x8 kv[4], vv[4];
        #pragma unroll
        for (int s = 0; s < 4; ++s) {
            kv[s] = *(const bf16x8*)(Kb + (size_t)(kb + krow + 32 * s) * TDH + kcol);
            vv[s] = *(const bf16x8*)(Vb + (size_t)(vrow + 16 * s) * TT + kb + vcol);
        }
        __syncthreads();
        #pragma unroll
        for (int s = 0; s < 4; ++s) {
            *(bf16x8*)&Ks[(krow + 32 * s) * AP + kcol] = kv[s];
            *(bf16x8*)&Vs[(vrow + 16 * s) * VP + vcol] = vv[s];
        }
        __syncthreads();

        f32x4 st[8];
        #pragma unroll
        for (int g2 = 0; g2 < 8; ++g2) {
            bf16x8 af0 = *(const bf16x8*)&Ks[(16 * g2 + c) * AP + g * 8];
            bf16x8 af1 = *(const bf16x8*)&Ks[(16 * g2 + c) * AP + 32 + g * 8];
            f32x4 z = (f32x4){0.f, 0.f, 0.f, 0.f};
            z = __builtin_amdgcn_mfma_f32_16x16x32_bf16(af0, qf0, z, 0, 0, 0);
            z = __builtin_amdgcn_mfma_f32_16x16x32_bf16(af1, qf1, z, 0, 0, 0);
            st[g2] = z;
        }

        float sv[8][4];
        float mx = -1e30f;
        if (p == pmax) {            // diagonal pair: causal mask
            #pragma unroll
            for (int g2 = 0; g2 < 8; ++g2)
                #pragma unroll
                for (int r = 0; r < 4; ++r) {
                    int kcol2 = kb + 16 * g2 + 4 * g + r;
                    float v = (kcol2 > q_glob) ? -1e30f : st[g2][r] * ATT_SCALE;
                    sv[g2][r] = v;
                    mx = fmaxf(mx, v);
                }
        } else {
            #pragma unroll
            for (int g2 = 0; g2 < 8; ++g2)
                #pragma unroll
                for (int r = 0; r < 4; ++r) {
                    float v = st[g2][r] * ATT_SCALE;
                    sv[g2][r] = v;
                    mx = fmaxf(mx, v);
                }
        }
        mx = fmaxf(mx, __shfl_xor(mx, 16));
        mx = fmaxf(mx, __shfl_xor(mx, 32));

        float nm = m_i;
        if (!__all(mx <= m_i + 8.0f)) {
            nm = fmaxf(m_i, mx);
            float corr = exp2f(m_i - nm);
            l_i *= corr;
            #pragma unroll
            for (int m2 = 0; m2 < 4; ++m2) {
                acc[m2][0] *= corr; acc[m2][1] *= corr;
                acc[m2][2] *= corr; acc[m2][3] *= corr;
            }
            m_i = nm;
        }

        float ps = 0.f;
        #pragma unroll
        for (int g2 = 0; g2 < 8; ++g2) {
            bf16x4 pk;
            #pragma unroll
            for (int r = 0; r < 4; ++r) {
                float pp = exp2f(sv[g2][r] - nm);
                ps += pp;
                pk[r] = (__bf16)pp;
            }
            *(bf16x4*)&Ps[(wave * 16 + c) * VP + 16 * g2 + 4 * g] = pk;
        }
        ps += __shfl_xor(ps, 16);
        ps += __shfl_xor(ps, 32);
        l_i += ps;

        bf16x8 pf[4];
        #pragma unroll
        for (int s = 0; s < 4; ++s)
            pf[s] = *(const bf16x8*)&Ps[(wave * 16 + c) * VP + 32 * s + g * 8];
        #pragma unroll
        for (int m2 = 0; m2 < 4; ++m2) {
            #pragma unroll
            for (int s = 0; s < 4; ++s) {
                bf16x8 vf = *(const bf16x8*)&Vs[(16 * m2 + c) * VP + 32 * s + g * 8];
                acc[m2] = __builtin_amdgcn_mfma_f32_16x16x32_bf16(vf, pf[s], acc[m2], 0, 0, 0);
            }
        }
    }

    const int b = bh / TH, h = bh - b * TH;
    float inv = 1.0f / l_i;
    #pragma unroll
    for (int m2 = 0; m2 < 4; ++m2) {
        bf16x4 o;
        #pragma unroll
        for (int r = 0; r < 4; ++r)
            o[r] = (__bf16)(acc[m2][r] * inv);
        *(bf16x4*)(ctx + ((size_t)b * TT + q_glob) * TC + h * TDH + 16 * m2 + 4 * g) = o;
    }
}

// ---------------------------------------------------------------------------
extern "C" void kernel_launch(void* const* d_in, const int* in_sizes, int n_in,
                              void* d_out, int out_size, void* d_ws, size_t ws_size,
                              hipStream_t stream)
{
    const float* x    = (const float*)d_in[0];
    const float* Wq   = (const float*)d_in[1];
    const float* bq   = (const float*)d_in[2];
    const float* Wk   = (const float*)d_in[3];
    const float* bk   = (const float*)d_in[4];
    const float* Wv   = (const float*)d_in[5];
    const float* bv   = (const float*)d_in[6];
    const float* Wo   = (const float*)d_in[7];
    const float* bo   = (const float*)d_in[8];
    const float* ln1s = (const float*)d_in[9];
    const float* ln1b = (const float*)d_in[10];
    const float* W1   = (const float*)d_in[11];
    const float* b1   = (const float*)d_in[12];
    const float* W2   = (const float*)d_in[13];
    const float* b2   = (const float*)d_in[14];
    const float* ln2s = (const float*)d_in[15];
    const float* ln2b = (const float*)d_in[16];
    float* out = (float*)d_out;

    const size_t MC  = (size_t)TM * TC;       // 3,145,728 elems
    const size_t MCB = MC * 2;                // bytes of one bf16 [TM,TC]
    const size_t WSZ = (size_t)TC * TC;
    const size_t W12 = (size_t)TC * TI;

    char* W = (char*)d_ws;
    __bf16* qkvb  = (__bf16*)W;
    __bf16* x_bf  = (__bf16*)(W + 3 * MCB);
    float*  tmp1  = (float*)W;
    __bf16* u_bf  = (__bf16*)W;
    __bf16* ctxh  = (__bf16*)(W + 6 * MCB);
    __bf16* wts   = (__bf16*)(W + 7 * MCB);
    __bf16* WqkvT = wts;
    __bf16* WoT   = WqkvT + 3 * WSZ;
    __bf16* W1T   = WoT + WSZ;
    __bf16* W2T   = W1T + W12;

    prep_kernel<<<dim3(1536 + 6912), dim3(256), 0, stream>>>(
        x, Wq, Wk, Wv, Wo, W1, W2, x_bf, WqkvT, WoT, W1T, W2T);

    // QKV: 128x128 tiles, 512 thr / 8 waves, grid 6x32x3 = 576 blocks
    gemm_mfma<128, 128, 64, 32, 512><<<dim3(TC / 128, TM / 128, 3), dim3(512), 0, stream>>>(
        x_bf, WqkvT, bq, bk, bv, nullptr, nullptr, qkvb, TC, TC, TC, WSZ, 0, MC, 0);

    attn_mfma<<<dim3(TT / 64, TB * TH), dim3(256), 0, stream>>>(
        qkvb, qkvb + MC, qkvb + 2 * MC, ctxh);

    // out-proj + residual(x): 64x64 tiles (measured best), grid 12x64 = 768
    gemm_mfma<64, 64, 32, 32, 256><<<dim3(TC / 64, TM / 64, 1), dim3(256), 0, stream>>>(
        ctxh, WoT, bo, nullptr, nullptr, x, tmp1, nullptr, TC, TC, TC, 0, 0, 0, 1);

    // ln1: bf16 h -> ctxh (MLP1 input) AND pre-init out = h + b2 (for split-K)
    ln_kernel<<<dim3(TM), dim3(256), 0, stream>>>(
        tmp1, ln1s, ln1b, nullptr, ctxh, b2, out);

    // MLP1 + gelu: 128x128 tiles, 512 thr / 8 waves, grid 24x32 = 768 blocks
    gemm_mfma<128, 128, 64, 32, 512><<<dim3(TI / 128, TM / 128, 1), dim3(512), 0, stream>>>(
        ctxh, W1T, b1, nullptr, nullptr, nullptr, nullptr, u_bf, TI, TC, TC, 0, 0, 0, 2);

    // MLP2 split-K=2: 64x64 tiles, grid 12x64x2 = 1536 blocks (6/CU);
    // each z-half accumulates K=1536 and atomicAdds into pre-inited out.
    gemm_mfma<64, 64, 32, 32, 256><<<dim3(TC / 64, TM / 64, 2), dim3(256), 0, stream>>>(
        u_bf, W2T, nullptr, nullptr, nullptr, nullptr, out, nullptr,
        TC, TI / 2, TI, (size_t)(TI / 2), (size_t)TI, 0, 3);

    ln_kernel<<<dim3(TM), dim3(256), 0, stream>>>(
        out, ln2s, ln2b, out, nullptr, nullptr, nullptr);
}

// Round 12
// 310.573 us; speedup vs baseline: 1.0521x; 1.0162x over previous
//
#include <hip/hip_runtime.h>
#include <math.h>

#define TB  2
#define TT  2048
#define TC  768
#define TH  12
#define TDH 64
#define TI  3072
#define TM  (TB*TT)   // 4096 rows

typedef __attribute__((ext_vector_type(8))) __bf16 bf16x8;
typedef __attribute__((ext_vector_type(4))) __bf16 bf16x4;
typedef __attribute__((ext_vector_type(4))) float  f32x4;

// gelu(x) = 0.5x(1+tanh(0.79788456*(x+0.044715x^3))) = x*sigmoid(2y)
//         = x / (1 + exp2(-2.30220829*(x+0.044715x^3)))   [exact identity]
// native v_exp_f32 + rcp instead of tanhf's ~15-20-inst expansion.
__device__ __forceinline__ float gelu_tanh(float x) {
    float u = x + 0.044715f * x * x * x;
    return x / (1.0f + exp2f(-2.30220829f * u));
}

// async global->LDS, 16B per lane (wave-uniform LDS base, lane l -> base+l*16)
__device__ __forceinline__ void gld_lds16(const void* g, void* l) {
    __builtin_amdgcn_global_load_lds(
        (const __attribute__((address_space(1))) unsigned int*)g,
        (__attribute__((address_space(3))) unsigned int*)l,
        16, 0, 0);
}

template<int N>
__device__ __forceinline__ void vmcnt_wait() {
    if constexpr (N == 0)      asm volatile("s_waitcnt vmcnt(0)" ::: "memory");
    else if constexpr (N == 2) asm volatile("s_waitcnt vmcnt(2)" ::: "memory");
    else if constexpr (N == 3) asm volatile("s_waitcnt vmcnt(3)" ::: "memory");
    else if constexpr (N == 4) asm volatile("s_waitcnt vmcnt(4)" ::: "memory");
    else if constexpr (N == 6) asm volatile("s_waitcnt vmcnt(6)" ::: "memory");
    else if constexpr (N == 8) asm volatile("s_waitcnt vmcnt(8)" ::: "memory");
    else static_assert(N == 0, "unsupported vmcnt");
}

// ---------------------------------------------------------------------------
// bf16 MFMA GEMM: distance-2 prefetch, templated threads.
// Round 12 = EXACT round-7 configuration (measured session-best, 312.0 us):
//   QKV/MLP1: 128x128, 512 thr / 8 waves   outproj/MLP2: 64x64, 256 thr
// Ledger: 64x128 outproj/MLP2 +1.3us (r9), 256x128 MLP1 +14.7us (r10),
// split-K MLP2 +3.6us (r11) — all deviations regressed; this is the optimum.
// ---------------------------------------------------------------------------
#define BK 32

template<int BM_, int BN_, int WM_, int WN_, int THREADS_>
__global__ __launch_bounds__(THREADS_)
void gemm_mfma(const __bf16* __restrict__ A, const __bf16* __restrict__ Bt,
               const float* __restrict__ b0, const float* __restrict__ b1,
               const float* __restrict__ b2, const float* __restrict__ resid,
               float* __restrict__ outf, __bf16* __restrict__ outb,
               int N, int K, size_t wt_stride, size_t out_stride, int ep)
{
    constexpr int WAVES_N = BN_ / WN_;
    constexpr int TMt = WM_ / 16, TNt = WN_ / 16;
    constexpr int RP   = THREADS_ / 4;              // staging rows per pass
    constexpr int AISS = BM_ / RP, BISS = BN_ / RP;
    constexpr int S    = AISS + BISS;               // gld_lds per thread/stage
    constexpr int PASS = THREADS_ * 16;             // bytes per staging pass
    constexpr int TILE = (BM_ + BN_) * BK;          // elems per buffer
    static_assert(AISS >= 1 && BISS >= 1, "tile too small for thread count");
    __shared__ __align__(16) __bf16 lds[3 * TILE];

    const int tid  = threadIdx.x;
    const int wave = tid >> 6, lane = tid & 63;
    const int wm = wave / WAVES_N, wn = wave % WAVES_N;
    const int m0 = blockIdx.y * BM_, n0 = blockIdx.x * BN_;
    const int z  = blockIdx.z;

    const __bf16* Bz = Bt + (size_t)z * wt_stride;
    const size_t Kb = (size_t)K * 2;
    const char* Ag = (const char*)A + (size_t)m0 * Kb;
    const char* Bg = (const char*)Bz + (size_t)n0 * Kb;
    const int srow = tid >> 2;
    const int scol = ((tid & 3) ^ ((tid >> 4) & 3)) * 16;   // swizzled src chunk
    const int wbase = wave * 1024;

    f32x4 acc[TMt][TNt];
    #pragma unroll
    for (int i = 0; i < TMt; ++i)
        #pragma unroll
        for (int j = 0; j < TNt; ++j)
            acc[i][j] = (f32x4){0.f, 0.f, 0.f, 0.f};

    const int arow = wm * WM_ + (lane & 15);
    const int brow = wn * WN_ + (lane & 15);
    const int koff = (((lane >> 4) ^ ((lane >> 2) & 3))) * 8;  // swizzled chunk

    const int nIter = K / BK;

    auto stage = [&](char* base, int k0b) {
        #pragma unroll
        for (int s = 0; s < AISS; ++s)
            gld_lds16(Ag + (size_t)(srow + RP * s) * Kb + k0b + scol,
                      base + s * PASS + wbase);
        char* bbase = base + BM_ * BK * 2;
        #pragma unroll
        for (int s = 0; s < BISS; ++s)
            gld_lds16(Bg + (size_t)(srow + RP * s) * Kb + k0b + scol,
                      bbase + s * PASS + wbase);
    };

    char* P0 = (char*)lds;
    char* P1 = P0 + (size_t)TILE * 2;
    char* P2 = P1 + (size_t)TILE * 2;

    stage(P0, 0);
    if (nIter > 1) stage(P1, BK * 2);
    __builtin_amdgcn_sched_barrier(0);   // pin prologue DMA issue order
    char* cur = P0; char* n1 = P1; char* n2 = P2;

    for (int it = 0; it < nIter; ++it) {
        if (it + 2 < nIter) stage(n2, (it + 2) * (BK * 2));
        __builtin_amdgcn_sched_barrier(0);       // DMA issued before the wait
        const int rem = nIter - 1 - it;          // stages in flight beyond it
        if (rem >= 2)      vmcnt_wait<2 * S>();
        else if (rem == 1) vmcnt_wait<S>();
        else               vmcnt_wait<0>();
        __builtin_amdgcn_s_barrier();            // barrier #1: tile-it ready
        __builtin_amdgcn_sched_barrier(0);

        const __bf16* As = (const __bf16*)cur;
        const __bf16* Bs = As + BM_ * BK;
        bf16x8 af[TMt], bfr[TNt];
        #pragma unroll
        for (int ti = 0; ti < TMt; ++ti)
            af[ti] = *(const bf16x8*)&As[(arow + ti * 16) * BK + koff];
        #pragma unroll
        for (int tj = 0; tj < TNt; ++tj)
            bfr[tj] = *(const bf16x8*)&Bs[(brow + tj * 16) * BK + koff];
        #pragma unroll
        for (int ti = 0; ti < TMt; ++ti)
            #pragma unroll
            for (int tj = 0; tj < TNt; ++tj)
                acc[ti][tj] = __builtin_amdgcn_mfma_f32_16x16x32_bf16(
                    af[ti], bfr[tj], acc[ti][tj], 0, 0, 0);

        __builtin_amdgcn_sched_barrier(0);
        __builtin_amdgcn_s_barrier();            // barrier #2: reads of cur done
        char* t = cur; cur = n1; n1 = n2; n2 = t;
    }

    // C/D: col = lane&15, row = (lane>>4)*4 + r
    const int lrow = m0 + wm * WM_ + ((lane >> 4) << 2);
    const int lcol = n0 + wn * WN_ + (lane & 15);

    if (ep == 0) {
        const float* bias = (z == 0) ? b0 : (z == 1) ? b1 : b2;
        __bf16* outz = outb + (size_t)z * out_stride;
        if (z < 2) {
            #pragma unroll
            for (int tj = 0; tj < TNt; ++tj) {
                int n = lcol + tj * 16;
                float bj = bias[n];
                int h = n >> 6, d = n & 63;
                #pragma unroll
                for (int ti = 0; ti < TMt; ++ti)
                    #pragma unroll
                    for (int r = 0; r < 4; ++r) {
                        int m = lrow + ti * 16 + r;
                        int b = m >> 11, t = m & (TT - 1);
                        outz[((size_t)(b * TH + h) * TT + t) * TDH + d] =
                            (__bf16)(acc[ti][tj][r] + bj);
                    }
            }
        } else {
            #pragma unroll
            for (int tj = 0; tj < TNt; ++tj) {
                int n = lcol + tj * 16;
                float bj = bias[n];
                int h = n >> 6, d = n & 63;
                #pragma unroll
                for (int ti = 0; ti < TMt; ++ti) {
                    int m = lrow + ti * 16;
                    int b = m >> 11, t0 = m & (TT - 1);
                    bf16x4 pk;
                    #pragma unroll
                    for (int r = 0; r < 4; ++r)
                        pk[r] = (__bf16)(acc[ti][tj][r] + bj);
                    *(bf16x4*)(outz + ((size_t)(b * TH + h) * TDH + d) * TT + t0) = pk;
                }
            }
        }
    } else if (ep == 1) {
        #pragma unroll
        for (int tj = 0; tj < TNt; ++tj) {
            int n = lcol + tj * 16;
            float bj = b0[n];
            #pragma unroll
            for (int ti = 0; ti < TMt; ++ti)
                #pragma unroll
                for (int r = 0; r < 4; ++r) {
                    int m = lrow + ti * 16 + r;
                    outf[(size_t)m * N + n] =
                        acc[ti][tj][r] + bj + resid[(size_t)m * N + n];
                }
        }
    } else {
        #pragma unroll
        for (int tj = 0; tj < TNt; ++tj) {
            int n = lcol + tj * 16;
            float bj = b0[n];
            #pragma unroll
            for (int ti = 0; ti < TMt; ++ti)
                #pragma unroll
                for (int r = 0; r < 4; ++r) {
                    int m = lrow + ti * 16 + r;
                    outb[(size_t)m * N + n] = (__bf16)gelu_tanh(acc[ti][tj][r] + bj);
                }
        }
    }
}

// ---------------------------------------------------------------------------
// Fused prep: x fp32->bf16 (blocks [0,1536)) + 6 weight transposes to bf16
// ---------------------------------------------------------------------------
__global__ __launch_bounds__(256)
void prep_kernel(const float* __restrict__ x,
                 const float* __restrict__ Wq, const float* __restrict__ Wk,
                 const float* __restrict__ Wv, const float* __restrict__ Wo,
                 const float* __restrict__ W1, const float* __restrict__ W2,
                 __bf16* __restrict__ x_bf, __bf16* __restrict__ WqkvT,
                 __bf16* __restrict__ WoT, __bf16* __restrict__ W1T,
                 __bf16* __restrict__ W2T)
{
    const size_t WSZ = (size_t)TC * TC;
    int bid = blockIdx.x;
    if (bid < 1536) {                        // x conversion: 1536*256*8 = MC
        int i = (bid * 256 + threadIdx.x) * 8;
        float4 a = *(const float4*)(x + i);
        float4 b = *(const float4*)(x + i + 4);
        bf16x8 v;
        v[0] = (__bf16)a.x; v[1] = (__bf16)a.y; v[2] = (__bf16)a.z; v[3] = (__bf16)a.w;
        v[4] = (__bf16)b.x; v[5] = (__bf16)b.y; v[6] = (__bf16)b.z; v[7] = (__bf16)b.w;
        *(bf16x8*)(x_bf + i) = v;
        return;
    }
    bid -= 1536;
    const float* src; __bf16* dst; int K, N, tloc;
    if (bid < 2304) {            // Wq/Wk/Wv/Wo: 576 tiles each
        int w = bid / 576; tloc = bid - w * 576;
        K = TC; N = TC;
        src = (w == 0) ? Wq : (w == 1) ? Wk : (w == 2) ? Wv : Wo;
        dst = (w < 3) ? (WqkvT + (size_t)w * WSZ) : WoT;
    } else if (bid < 4608) {     // W1 [768,3072]
        tloc = bid - 2304; K = TC; N = TI; src = W1; dst = W1T;
    } else {                     // W2 [3072,768]
        tloc = bid - 4608; K = TI; N = TC; src = W2; dst = W2T;
    }
    int tiles_x = N >> 5;
    int n0 = (tloc % tiles_x) * 32, k0 = (tloc / tiles_x) * 32;

    __shared__ float tile[32][33];
    const int tx = threadIdx.x & 31, ty = threadIdx.x >> 5;
    #pragma unroll
    for (int i = 0; i < 32; i += 8)
        tile[ty + i][tx] = src[(size_t)(k0 + ty + i) * N + n0 + tx];
    __syncthreads();
    #pragma unroll
    for (int i = 0; i < 32; i += 8)
        dst[(size_t)(n0 + ty + i) * K + k0 + tx] = (__bf16)tile[tx][ty + i];
}

// ---------------------------------------------------------------------------
// LayerNorm (ddof=1, EPS=1e-4), optional bf16 copy
// ---------------------------------------------------------------------------
__global__ __launch_bounds__(256)
void ln_kernel(const float* __restrict__ in, const float* __restrict__ gs,
               const float* __restrict__ gb, float* __restrict__ out,
               __bf16* __restrict__ out_bf)
{
    const int row = blockIdx.x, tid = threadIdx.x;
    const float* r = in + (size_t)row * TC;
    float x0 = r[tid], x1 = r[tid + 256], x2 = r[tid + 512];
    float s = x0 + x1 + x2;
    float q = x0 * x0 + x1 * x1 + x2 * x2;
    #pragma unroll
    for (int off = 32; off > 0; off >>= 1) {
        s += __shfl_down(s, off);
        q += __shfl_down(q, off);
    }
    __shared__ float partial[8];
    __shared__ float stats[2];
    int wid = tid >> 6, lane = tid & 63;
    if (lane == 0) { partial[wid] = s; partial[wid + 4] = q; }
    __syncthreads();
    if (tid == 0) {
        float S = partial[0] + partial[1] + partial[2] + partial[3];
        float Q = partial[4] + partial[5] + partial[6] + partial[7];
        float mean = S * (1.0f / (float)TC);
        float var = (Q - (float)TC * mean * mean) * (1.0f / (float)(TC - 1));
        stats[0] = mean;
        stats[1] = rsqrtf(var + 1e-4f);
    }
    __syncthreads();
    float mean = stats[0], rstd = stats[1];
    float* w = out + (size_t)row * TC;
    float y0 = gs[tid]       * ((x0 - mean) * rstd) + gb[tid];
    float y1 = gs[tid + 256] * ((x1 - mean) * rstd) + gb[tid + 256];
    float y2 = gs[tid + 512] * ((x2 - mean) * rstd) + gb[tid + 512];
    w[tid] = y0; w[tid + 256] = y1; w[tid + 512] = y2;
    if (out_bf) {
        __bf16* wb = out_bf + (size_t)row * TC;
        wb[tid] = (__bf16)y0; wb[tid + 256] = (__bf16)y1; wb[tid + 512] = (__bf16)y2;
    }
}

// ---------------------------------------------------------------------------
// MFMA flash attention v4 (round-6/9 version, best measured 62.5 us):
// 768-block snake, 3 blocks/CU, KVBLK=128 per iter, defer-max, exp2 softmax.
// ---------------------------------------------------------------------------
#define AP 72
#define VP 136
#define ATT_SCALE 0.18033688011112042f   /* 0.125 * log2(e) */

__global__ __launch_bounds__(256)
void attn_mfma(const __bf16* __restrict__ Q, const __bf16* __restrict__ K,
               const __bf16* __restrict__ Vt, __bf16* __restrict__ ctx)
{
    __shared__ __align__(16) __bf16 Ks[128 * AP];
    __shared__ __align__(16) __bf16 Vs[64 * VP];
    __shared__ __align__(16) __bf16 Ps[64 * VP];

    const int tid  = threadIdx.x;
    const int wave = tid >> 6, lane = tid & 63;
    const int c = lane & 15, g = lane >> 4;
    const int bh = blockIdx.y;
    const int qi = blockIdx.x;
    const int qt = (qi & 1) ? (31 - (qi >> 1)) : (qi >> 1);
    const int q_glob = qt * 64 + wave * 16 + c;

    const __bf16* Qb = Q  + (size_t)bh * TT * TDH;
    const __bf16* Kb = K  + (size_t)bh * TT * TDH;
    const __bf16* Vb = Vt + (size_t)bh * TDH * TT;

    bf16x8 qf0 = *(const bf16x8*)(Qb + (size_t)q_glob * TDH + g * 8);
    bf16x8 qf1 = *(const bf16x8*)(Qb + (size_t)q_glob * TDH + 32 + g * 8);

    const int krow = tid >> 3, kcol = (tid & 7) * 8;
    const int vrow = tid >> 4, vcol = (tid & 15) * 8;

    float m_i = -1e30f, l_i = 0.0f;
    f32x4 acc[4];
    #pragma unroll
    for (int m2 = 0; m2 < 4; ++m2) acc[m2] = (f32x4){0.f, 0.f, 0.f, 0.f};

    const int pmax = qt >> 1;
    for (int p = 0; p <= pmax; ++p) {
        const int kb = p * 128;
        bf16x8 kv[4], vv[4];
        #pragma unroll
        for (int s = 0; s < 4; ++s) {
            kv[s] = *(const bf16x8*)(Kb + (size_t)(kb + krow + 32 * s) * TDH + kcol);
            vv[s] = *(const bf16x8*)(Vb + (size_t)(vrow + 16 * s) * TT + kb + vcol);
        }
        __syncthreads();
        #pragma unroll
        for (int s = 0; s < 4; ++s) {
            *(bf16x8*)&Ks[(krow + 32 * s) * AP + kcol] = kv[s];
            *(bf16x8*)&Vs[(vrow + 16 * s) * VP + vcol] = vv[s];
        }
        __syncthreads();

        f32x4 st[8];
        #pragma unroll
        for (int g2 = 0; g2 < 8; ++g2) {
            bf16x8 af0 = *(const bf16x8*)&Ks[(16 * g2 + c) * AP + g * 8];
            bf16x8 af1 = *(const bf16x8*)&Ks[(16 * g2 + c) * AP + 32 + g * 8];
            f32x4 z = (f32x4){0.f, 0.f, 0.f, 0.f};
            z = __builtin_amdgcn_mfma_f32_16x16x32_bf16(af0, qf0, z, 0, 0, 0);
            z = __builtin_amdgcn_mfma_f32_16x16x32_bf16(af1, qf1, z, 0, 0, 0);
            st[g2] = z;
        }

        float sv[8][4];
        float mx = -1e30f;
        if (p == pmax) {            // diagonal pair: causal mask
            #pragma unroll
            for (int g2 = 0; g2 < 8; ++g2)
                #pragma unroll
                for (int r = 0; r < 4; ++r) {
                    int kcol2 = kb + 16 * g2 + 4 * g + r;
                    float v = (kcol2 > q_glob) ? -1e30f : st[g2][r] * ATT_SCALE;
                    sv[g2][r] = v;
                    mx = fmaxf(mx, v);
                }
        } else {
            #pragma unroll
            for (int g2 = 0; g2 < 8; ++g2)
                #pragma unroll
                for (int r = 0; r < 4; ++r) {
                    float v = st[g2][r] * ATT_SCALE;
                    sv[g2][r] = v;
                    mx = fmaxf(mx, v);
                }
        }
        mx = fmaxf(mx, __shfl_xor(mx, 16));
        mx = fmaxf(mx, __shfl_xor(mx, 32));

        float nm = m_i;
        if (!__all(mx <= m_i + 8.0f)) {
            nm = fmaxf(m_i, mx);
            float corr = exp2f(m_i - nm);
            l_i *= corr;
            #pragma unroll
            for (int m2 = 0; m2 < 4; ++m2) {
                acc[m2][0] *= corr; acc[m2][1] *= corr;
                acc[m2][2] *= corr; acc[m2][3] *= corr;
            }
            m_i = nm;
        }

        float ps = 0.f;
        #pragma unroll
        for (int g2 = 0; g2 < 8; ++g2) {
            bf16x4 pk;
            #pragma unroll
            for (int r = 0; r < 4; ++r) {
                float pp = exp2f(sv[g2][r] - nm);
                ps += pp;
                pk[r] = (__bf16)pp;
            }
            *(bf16x4*)&Ps[(wave * 16 + c) * VP + 16 * g2 + 4 * g] = pk;
        }
        ps += __shfl_xor(ps, 16);
        ps += __shfl_xor(ps, 32);
        l_i += ps;

        bf16x8 pf[4];
        #pragma unroll
        for (int s = 0; s < 4; ++s)
            pf[s] = *(const bf16x8*)&Ps[(wave * 16 + c) * VP + 32 * s + g * 8];
        #pragma unroll
        for (int m2 = 0; m2 < 4; ++m2) {
            #pragma unroll
            for (int s = 0; s < 4; ++s) {
                bf16x8 vf = *(const bf16x8*)&Vs[(16 * m2 + c) * VP + 32 * s + g * 8];
                acc[m2] = __builtin_amdgcn_mfma_f32_16x16x32_bf16(vf, pf[s], acc[m2], 0, 0, 0);
            }
        }
    }

    const int b = bh / TH, h = bh - b * TH;
    float inv = 1.0f / l_i;
    #pragma unroll
    for (int m2 = 0; m2 < 4; ++m2) {
        bf16x4 o;
        #pragma unroll
        for (int r = 0; r < 4; ++r)
            o[r] = (__bf16)(acc[m2][r] * inv);
        *(bf16x4*)(ctx + ((size_t)b * TT + q_glob) * TC + h * TDH + 16 * m2 + 4 * g) = o;
    }
}

// ---------------------------------------------------------------------------
extern "C" void kernel_launch(void* const* d_in, const int* in_sizes, int n_in,
                              void* d_out, int out_size, void* d_ws, size_t ws_size,
                              hipStream_t stream)
{
    const float* x    = (const float*)d_in[0];
    const float* Wq   = (const float*)d_in[1];
    const float* bq   = (const float*)d_in[2];
    const float* Wk   = (const float*)d_in[3];
    const float* bk   = (const float*)d_in[4];
    const float* Wv   = (const float*)d_in[5];
    const float* bv   = (const float*)d_in[6];
    const float* Wo   = (const float*)d_in[7];
    const float* bo   = (const float*)d_in[8];
    const float* ln1s = (const float*)d_in[9];
    const float* ln1b = (const float*)d_in[10];
    const float* W1   = (const float*)d_in[11];
    const float* b1   = (const float*)d_in[12];
    const float* W2   = (const float*)d_in[13];
    const float* b2   = (const float*)d_in[14];
    const float* ln2s = (const float*)d_in[15];
    const float* ln2b = (const float*)d_in[16];
    float* out = (float*)d_out;

    const size_t MC  = (size_t)TM * TC;       // 3,145,728 elems
    const size_t MCB = MC * 2;                // bytes of one bf16 [TM,TC]
    const size_t WSZ = (size_t)TC * TC;
    const size_t W12 = (size_t)TC * TI;

    char* W = (char*)d_ws;
    __bf16* qkvb  = (__bf16*)W;
    __bf16* x_bf  = (__bf16*)(W + 3 * MCB);
    float*  tmp1  = (float*)W;
    __bf16* u_bf  = (__bf16*)W;
    float*  h_f32 = (float*)(W + 4 * MCB);
    __bf16* ctxh  = (__bf16*)(W + 6 * MCB);
    __bf16* wts   = (__bf16*)(W + 7 * MCB);
    __bf16* WqkvT = wts;
    __bf16* WoT   = WqkvT + 3 * WSZ;
    __bf16* W1T   = WoT + WSZ;
    __bf16* W2T   = W1T + W12;

    prep_kernel<<<dim3(1536 + 6912), dim3(256), 0, stream>>>(
        x, Wq, Wk, Wv, Wo, W1, W2, x_bf, WqkvT, WoT, W1T, W2T);

    // QKV: 128x128 tiles, 512 thr / 8 waves, grid 6x32x3 = 576 blocks
    gemm_mfma<128, 128, 64, 32, 512><<<dim3(TC / 128, TM / 128, 3), dim3(512), 0, stream>>>(
        x_bf, WqkvT, bq, bk, bv, nullptr, nullptr, qkvb, TC, TC, WSZ, MC, 0);

    attn_mfma<<<dim3(TT / 64, TB * TH), dim3(256), 0, stream>>>(
        qkvb, qkvb + MC, qkvb + 2 * MC, ctxh);

    // out-proj + residual(x): 64x64 tiles (measured best), grid 12x64 = 768
    gemm_mfma<64, 64, 32, 32, 256><<<dim3(TC / 64, TM / 64, 1), dim3(256), 0, stream>>>(
        ctxh, WoT, bo, nullptr, nullptr, x, tmp1, nullptr, TC, TC, 0, 0, 1);

    ln_kernel<<<dim3(TM), dim3(256), 0, stream>>>(tmp1, ln1s, ln1b, h_f32, ctxh);

    // MLP1 + gelu: 128x128 tiles, 512 thr / 8 waves, grid 24x32 = 768 blocks
    gemm_mfma<128, 128, 64, 32, 512><<<dim3(TI / 128, TM / 128, 1), dim3(512), 0, stream>>>(
        ctxh, W1T, b1, nullptr, nullptr, nullptr, nullptr, u_bf, TI, TC, 0, 0, 2);

    // MLP2 + residual(h): 64x64 tiles (measured best), grid 12x64 = 768
    gemm_mfma<64, 64, 32, 32, 256><<<dim3(TC / 64, TM / 64, 1), dim3(256), 0, stream>>>(
        u_bf, W2T, b2, nullptr, nullptr, h_f32, out, nullptr, TC, TI, 0, 0, 1);

    ln_kernel<<<dim3(TM), dim3(256), 0, stream>>>(out, ln2s, ln2b, out, nullptr);
}

// Round 14
// 299.105 us; speedup vs baseline: 1.0924x; 1.0383x over previous
//
#include <hip/hip_runtime.h>
#include <math.h>

#define TB  2
#define TT  2048
#define TC  768
#define TH  12
#define TDH 64
#define TI  3072
#define TM  (TB*TT)   // 4096 rows

typedef __attribute__((ext_vector_type(8))) __bf16 bf16x8;
typedef __attribute__((ext_vector_type(4))) __bf16 bf16x4;
typedef __attribute__((ext_vector_type(4))) float  f32x4;

// gelu(x) = 0.5x(1+tanh(0.79788456*(x+0.044715x^3))) = x*sigmoid(2y)
//         = x / (1 + exp2(-2.30220829*(x+0.044715x^3)))   [exact identity]
__device__ __forceinline__ float gelu_tanh(float x) {
    float u = x + 0.044715f * x * x * x;
    return x / (1.0f + exp2f(-2.30220829f * u));
}

// async global->LDS, 16B per lane (wave-uniform LDS base, lane l -> base+l*16)
__device__ __forceinline__ void gld_lds16(const void* g, void* l) {
    __builtin_amdgcn_global_load_lds(
        (const __attribute__((address_space(1))) unsigned int*)g,
        (__attribute__((address_space(3))) unsigned int*)l,
        16, 0, 0);
}

template<int N>
__device__ __forceinline__ void vmcnt_wait() {
    if constexpr (N == 0)      asm volatile("s_waitcnt vmcnt(0)" ::: "memory");
    else if constexpr (N == 2) asm volatile("s_waitcnt vmcnt(2)" ::: "memory");
    else if constexpr (N == 3) asm volatile("s_waitcnt vmcnt(3)" ::: "memory");
    else if constexpr (N == 4) asm volatile("s_waitcnt vmcnt(4)" ::: "memory");
    else if constexpr (N == 6) asm volatile("s_waitcnt vmcnt(6)" ::: "memory");
    else if constexpr (N == 8) asm volatile("s_waitcnt vmcnt(8)" ::: "memory");
    else static_assert(N == 0, "unsupported vmcnt");
}

// ---------------------------------------------------------------------------
// bf16 MFMA GEMM: distance-2 prefetch, templated threads + BK.
// Round 14 = round-13 resubmit (container failed twice, unobserved — round-3
// precedent was infra; full geometry audit found no hazard; BK=32 paths are
// byte-identical to the round-12 build that passed at 310.6us).
// outproj/MLP2: BK_=64 (iters 24->12 / 96->48, MFMA/wave-iter 4->8) at
// UNCHANGED residency (48KB LDS -> 3 blocks/CU). QKV/MLP1 stay BK=32.
// BK-generic XOR swizzle:
//   store: phys chunk (tid%CH) holds global chunk (tid%CH)^swz(row),
//          swz(r) = (r>>2)&3 [BK32] / r&7 [BK64]; pass-invariant (RP%8==0).
//   read:  koff = ((kk*4 + (lane>>4)) ^ swzr)*8; rows hit satisfy
//          row-swz == lane-derived swzr (audited: wm/ti offsets ≡ 0 mod 8).
// ---------------------------------------------------------------------------
template<int BM_, int BN_, int WM_, int WN_, int THREADS_, int BK_>
__global__ __launch_bounds__(THREADS_)
void gemm_mfma(const __bf16* __restrict__ A, const __bf16* __restrict__ Bt,
               const float* __restrict__ b0, const float* __restrict__ b1,
               const float* __restrict__ b2, const float* __restrict__ resid,
               float* __restrict__ outf, __bf16* __restrict__ outb,
               int N, int K, size_t wt_stride, size_t out_stride, int ep)
{
    constexpr int WAVES_N = BN_ / WN_;
    constexpr int TMt = WM_ / 16, TNt = WN_ / 16;
    constexpr int KSTEPS = BK_ / 32;                // MFMA k-steps per tile
    constexpr int CH   = BK_ * 2 / 16;              // 16B chunks per row (4|8)
    constexpr int RP   = THREADS_ / CH;             // staging rows per pass
    constexpr int AISS = BM_ / RP, BISS = BN_ / RP;
    constexpr int S    = AISS + BISS;               // gld_lds per thread/stage
    constexpr int PASS = THREADS_ * 16;             // bytes per staging pass
    constexpr int TILE = (BM_ + BN_) * BK_;         // elems per buffer
    static_assert(AISS >= 1 && BISS >= 1, "tile too small for thread count");
    __shared__ __align__(16) __bf16 lds[3 * TILE];

    const int tid  = threadIdx.x;
    const int wave = tid >> 6, lane = tid & 63;
    const int wm = wave / WAVES_N, wn = wave % WAVES_N;
    const int m0 = blockIdx.y * BM_, n0 = blockIdx.x * BN_;
    const int z  = blockIdx.z;

    const __bf16* Bz = Bt + (size_t)z * wt_stride;
    const size_t Kb = (size_t)K * 2;
    const char* Ag = (const char*)A + (size_t)m0 * Kb;
    const char* Bg = (const char*)Bz + (size_t)n0 * Kb;
    const int srow = tid / CH;
    const int sswz = (BK_ == 32) ? ((srow >> 2) & 3) : (srow & 7);   // pass-invariant
    const int scol = ((tid & (CH - 1)) ^ sswz) * 16;                 // global src chunk
    const int wbase = wave * 1024;

    f32x4 acc[TMt][TNt];
    #pragma unroll
    for (int i = 0; i < TMt; ++i)
        #pragma unroll
        for (int j = 0; j < TNt; ++j)
            acc[i][j] = (f32x4){0.f, 0.f, 0.f, 0.f};

    const int arow = wm * WM_ + (lane & 15);
    const int brow = wn * WN_ + (lane & 15);
    const int swzr = (BK_ == 32) ? ((lane >> 2) & 3) : (lane & 7);   // row-derived

    const int nIter = K / BK_;

    auto stage = [&](char* base, int k0b) {
        #pragma unroll
        for (int s = 0; s < AISS; ++s)
            gld_lds16(Ag + (size_t)(srow + RP * s) * Kb + k0b + scol,
                      base + s * PASS + wbase);
        char* bbase = base + BM_ * BK_ * 2;
        #pragma unroll
        for (int s = 0; s < BISS; ++s)
            gld_lds16(Bg + (size_t)(srow + RP * s) * Kb + k0b + scol,
                      bbase + s * PASS + wbase);
    };

    char* P0 = (char*)lds;
    char* P1 = P0 + (size_t)TILE * 2;
    char* P2 = P1 + (size_t)TILE * 2;

    stage(P0, 0);
    if (nIter > 1) stage(P1, BK_ * 2);
    __builtin_amdgcn_sched_barrier(0);   // pin prologue DMA issue order
    char* cur = P0; char* n1 = P1; char* n2 = P2;

    for (int it = 0; it < nIter; ++it) {
        if (it + 2 < nIter) stage(n2, (it + 2) * (BK_ * 2));
        __builtin_amdgcn_sched_barrier(0);       // DMA issued before the wait
        const int rem = nIter - 1 - it;          // stages in flight beyond it
        if (rem >= 2)      vmcnt_wait<2 * S>();
        else if (rem == 1) vmcnt_wait<S>();
        else               vmcnt_wait<0>();
        __builtin_amdgcn_s_barrier();            // barrier #1: tile-it ready
        __builtin_amdgcn_sched_barrier(0);

        const __bf16* As = (const __bf16*)cur;
        const __bf16* Bs = As + BM_ * BK_;
        #pragma unroll
        for (int kk = 0; kk < KSTEPS; ++kk) {
            const int koff = (((kk << 2) + (lane >> 4)) ^ swzr) * 8;
            bf16x8 af[TMt], bfr[TNt];
            #pragma unroll
            for (int ti = 0; ti < TMt; ++ti)
                af[ti] = *(const bf16x8*)&As[(arow + ti * 16) * BK_ + koff];
            #pragma unroll
            for (int tj = 0; tj < TNt; ++tj)
                bfr[tj] = *(const bf16x8*)&Bs[(brow + tj * 16) * BK_ + koff];
            #pragma unroll
            for (int ti = 0; ti < TMt; ++ti)
                #pragma unroll
                for (int tj = 0; tj < TNt; ++tj)
                    acc[ti][tj] = __builtin_amdgcn_mfma_f32_16x16x32_bf16(
                        af[ti], bfr[tj], acc[ti][tj], 0, 0, 0);
        }

        __builtin_amdgcn_sched_barrier(0);
        __builtin_amdgcn_s_barrier();            // barrier #2: reads of cur done
        char* t = cur; cur = n1; n1 = n2; n2 = t;
    }

    // C/D: col = lane&15, row = (lane>>4)*4 + r
    const int lrow = m0 + wm * WM_ + ((lane >> 4) << 2);
    const int lcol = n0 + wn * WN_ + (lane & 15);

    if (ep == 0) {
        const float* bias = (z == 0) ? b0 : (z == 1) ? b1 : b2;
        __bf16* outz = outb + (size_t)z * out_stride;
        if (z < 2) {
            #pragma unroll
            for (int tj = 0; tj < TNt; ++tj) {
                int n = lcol + tj * 16;
                float bj = bias[n];
                int h = n >> 6, d = n & 63;
                #pragma unroll
                for (int ti = 0; ti < TMt; ++ti)
                    #pragma unroll
                    for (int r = 0; r < 4; ++r) {
                        int m = lrow + ti * 16 + r;
                        int b = m >> 11, t = m & (TT - 1);
                        outz[((size_t)(b * TH + h) * TT + t) * TDH + d] =
                            (__bf16)(acc[ti][tj][r] + bj);
                    }
            }
        } else {
            #pragma unroll
            for (int tj = 0; tj < TNt; ++tj) {
                int n = lcol + tj * 16;
                float bj = bias[n];
                int h = n >> 6, d = n & 63;
                #pragma unroll
                for (int ti = 0; ti < TMt; ++ti) {
                    int m = lrow + ti * 16;
                    int b = m >> 11, t0 = m & (TT - 1);
                    bf16x4 pk;
                    #pragma unroll
                    for (int r = 0; r < 4; ++r)
                        pk[r] = (__bf16)(acc[ti][tj][r] + bj);
                    *(bf16x4*)(outz + ((size_t)(b * TH + h) * TDH + d) * TT + t0) = pk;
                }
            }
        }
    } else if (ep == 1) {
        #pragma unroll
        for (int tj = 0; tj < TNt; ++tj) {
            int n = lcol + tj * 16;
            float bj = b0[n];
            #pragma unroll
            for (int ti = 0; ti < TMt; ++ti)
                #pragma unroll
                for (int r = 0; r < 4; ++r) {
                    int m = lrow + ti * 16 + r;
                    outf[(size_t)m * N + n] =
                        acc[ti][tj][r] + bj + resid[(size_t)m * N + n];
                }
        }
    } else {
        #pragma unroll
        for (int tj = 0; tj < TNt; ++tj) {
            int n = lcol + tj * 16;
            float bj = b0[n];
            #pragma unroll
            for (int ti = 0; ti < TMt; ++ti)
                #pragma unroll
                for (int r = 0; r < 4; ++r) {
                    int m = lrow + ti * 16 + r;
                    outb[(size_t)m * N + n] = (__bf16)gelu_tanh(acc[ti][tj][r] + bj);
                }
        }
    }
}

// ---------------------------------------------------------------------------
// Fused prep: x fp32->bf16 (blocks [0,1536)) + 6 weight transposes to bf16
// ---------------------------------------------------------------------------
__global__ __launch_bounds__(256)
void prep_kernel(const float* __restrict__ x,
                 const float* __restrict__ Wq, const float* __restrict__ Wk,
                 const float* __restrict__ Wv, const float* __restrict__ Wo,
                 const float* __restrict__ W1, const float* __restrict__ W2,
                 __bf16* __restrict__ x_bf, __bf16* __restrict__ WqkvT,
                 __bf16* __restrict__ WoT, __bf16* __restrict__ W1T,
                 __bf16* __restrict__ W2T)
{
    const size_t WSZ = (size_t)TC * TC;
    int bid = blockIdx.x;
    if (bid < 1536) {                        // x conversion: 1536*256*8 = MC
        int i = (bid * 256 + threadIdx.x) * 8;
        float4 a = *(const float4*)(x + i);
        float4 b = *(const float4*)(x + i + 4);
        bf16x8 v;
        v[0] = (__bf16)a.x; v[1] = (__bf16)a.y; v[2] = (__bf16)a.z; v[3] = (__bf16)a.w;
        v[4] = (__bf16)b.x; v[5] = (__bf16)b.y; v[6] = (__bf16)b.z; v[7] = (__bf16)b.w;
        *(bf16x8*)(x_bf + i) = v;
        return;
    }
    bid -= 1536;
    const float* src; __bf16* dst; int K, N, tloc;
    if (bid < 2304) {            // Wq/Wk/Wv/Wo: 576 tiles each
        int w = bid / 576; tloc = bid - w * 576;
        K = TC; N = TC;
        src = (w == 0) ? Wq : (w == 1) ? Wk : (w == 2) ? Wv : Wo;
        dst = (w < 3) ? (WqkvT + (size_t)w * WSZ) : WoT;
    } else if (bid < 4608) {     // W1 [768,3072]
        tloc = bid - 2304; K = TC; N = TI; src = W1; dst = W1T;
    } else {                     // W2 [3072,768]
        tloc = bid - 4608; K = TI; N = TC; src = W2; dst = W2T;
    }
    int tiles_x = N >> 5;
    int n0 = (tloc % tiles_x) * 32, k0 = (tloc / tiles_x) * 32;

    __shared__ float tile[32][33];
    const int tx = threadIdx.x & 31, ty = threadIdx.x >> 5;
    #pragma unroll
    for (int i = 0; i < 32; i += 8)
        tile[ty + i][tx] = src[(size_t)(k0 + ty + i) * N + n0 + tx];
    __syncthreads();
    #pragma unroll
    for (int i = 0; i < 32; i += 8)
        dst[(size_t)(n0 + ty + i) * K + k0 + tx] = (__bf16)tile[tx][ty + i];
}

// ---------------------------------------------------------------------------
// LayerNorm (ddof=1, EPS=1e-4), optional bf16 copy
// ---------------------------------------------------------------------------
__global__ __launch_bounds__(256)
void ln_kernel(const float* __restrict__ in, const float* __restrict__ gs,
               const float* __restrict__ gb, float* __restrict__ out,
               __bf16* __restrict__ out_bf)
{
    const int row = blockIdx.x, tid = threadIdx.x;
    const float* r = in + (size_t)row * TC;
    float x0 = r[tid], x1 = r[tid + 256], x2 = r[tid + 512];
    float s = x0 + x1 + x2;
    float q = x0 * x0 + x1 * x1 + x2 * x2;
    #pragma unroll
    for (int off = 32; off > 0; off >>= 1) {
        s += __shfl_down(s, off);
        q += __shfl_down(q, off);
    }
    __shared__ float partial[8];
    __shared__ float stats[2];
    int wid = tid >> 6, lane = tid & 63;
    if (lane == 0) { partial[wid] = s; partial[wid + 4] = q; }
    __syncthreads();
    if (tid == 0) {
        float S = partial[0] + partial[1] + partial[2] + partial[3];
        float Q = partial[4] + partial[5] + partial[6] + partial[7];
        float mean = S * (1.0f / (float)TC);
        float var = (Q - (float)TC * mean * mean) * (1.0f / (float)(TC - 1));
        stats[0] = mean;
        stats[1] = rsqrtf(var + 1e-4f);
    }
    __syncthreads();
    float mean = stats[0], rstd = stats[1];
    float* w = out + (size_t)row * TC;
    float y0 = gs[tid]       * ((x0 - mean) * rstd) + gb[tid];
    float y1 = gs[tid + 256] * ((x1 - mean) * rstd) + gb[tid + 256];
    float y2 = gs[tid + 512] * ((x2 - mean) * rstd) + gb[tid + 512];
    w[tid] = y0; w[tid + 256] = y1; w[tid + 512] = y2;
    if (out_bf) {
        __bf16* wb = out_bf + (size_t)row * TC;
        wb[tid] = (__bf16)y0; wb[tid + 256] = (__bf16)y1; wb[tid + 512] = (__bf16)y2;
    }
}

// ---------------------------------------------------------------------------
// MFMA flash attention v4 (round-6/9 version, best measured 62.5 us):
// 768-block snake, 3 blocks/CU, KVBLK=128 per iter, defer-max, exp2 softmax.
// ---------------------------------------------------------------------------
#define AP 72
#define VP 136
#define ATT_SCALE 0.18033688011112042f   /* 0.125 * log2(e) */

__global__ __launch_bounds__(256)
void attn_mfma(const __bf16* __restrict__ Q, const __bf16* __restrict__ K,
               const __bf16* __restrict__ Vt, __bf16* __restrict__ ctx)
{
    __shared__ __align__(16) __bf16 Ks[128 * AP];
    __shared__ __align__(16) __bf16 Vs[64 * VP];
    __shared__ __align__(16) __bf16 Ps[64 * VP];

    const int tid  = threadIdx.x;
    const int wave = tid >> 6, lane = tid & 63;
    const int c = lane & 15, g = lane >> 4;
    const int bh = blockIdx.y;
    const int qi = blockIdx.x;
    const int qt = (qi & 1) ? (31 - (qi >> 1)) : (qi >> 1);
    const int q_glob = qt * 64 + wave * 16 + c;

    const __bf16* Qb = Q  + (size_t)bh * TT * TDH;
    const __bf16* Kb = K  + (size_t)bh * TT * TDH;
    const __bf16* Vb = Vt + (size_t)bh * TDH * TT;

    bf16x8 qf0 = *(const bf16x8*)(Qb + (size_t)q_glob * TDH + g * 8);
    bf16x8 qf1 = *(const bf16x8*)(Qb + (size_t)q_glob * TDH + 32 + g * 8);

    const int krow = tid >> 3, kcol = (tid & 7) * 8;
    const int vrow = tid >> 4, vcol = (tid & 15) * 8;

    float m_i = -1e30f, l_i = 0.0f;
    f32x4 acc[4];
    #pragma unroll
    for (int m2 = 0; m2 < 4; ++m2) acc[m2] = (f32x4){0.f, 0.f, 0.f, 0.f};

    const int pmax = qt >> 1;
    for (int p = 0; p <= pmax; ++p) {
        const int kb = p * 128;
        bf16x8 kv[4], vv[4];
        #pragma unroll
        for (int s = 0; s < 4; ++s) {
            kv[s] = *(const bf16x8*)(Kb + (size_t)(kb + krow + 32 * s) * TDH + kcol);
            vv[s] = *(const bf16x8*)(Vb + (size_t)(vrow + 16 * s) * TT + kb + vcol);
        }
        __syncthreads();
        #pragma unroll
        for (int s = 0; s < 4; ++s) {
            *(bf16x8*)&Ks[(krow + 32 * s) * AP + kcol] = kv[s];
            *(bf16x8*)&Vs[(vrow + 16 * s) * VP + vcol] = vv[s];
        }
        __syncthreads();

        f32x4 st[8];
        #pragma unroll
        for (int g2 = 0; g2 < 8; ++g2) {
            bf16x8 af0 = *(const bf16x8*)&Ks[(16 * g2 + c) * AP + g * 8];
            bf16x8 af1 = *(const bf16x8*)&Ks[(16 * g2 + c) * AP + 32 + g * 8];
            f32x4 z = (f32x4){0.f, 0.f, 0.f, 0.f};
            z = __builtin_amdgcn_mfma_f32_16x16x32_bf16(af0, qf0, z, 0, 0, 0);
            z = __builtin_amdgcn_mfma_f32_16x16x32_bf16(af1, qf1, z, 0, 0, 0);
            st[g2] = z;
        }

        float sv[8][4];
        float mx = -1e30f;
        if (p == pmax) {            // diagonal pair: causal mask
            #pragma unroll
            for (int g2 = 0; g2 < 8; ++g2)
                #pragma unroll
                for (int r = 0; r < 4; ++r) {
                    int kcol2 = kb + 16 * g2 + 4 * g + r;
                    float v = (kcol2 > q_glob) ? -1e30f : st[g2][r] * ATT_SCALE;
                    sv[g2][r] = v;
                    mx = fmaxf(mx, v);
                }
        } else {
            #pragma unroll
            for (int g2 = 0; g2 < 8; ++g2)
                #pragma unroll
                for (int r = 0; r < 4; ++r) {
                    float v = st[g2][r] * ATT_SCALE;
                    sv[g2][r] = v;
                    mx = fmaxf(mx, v);
                }
        }
        mx = fmaxf(mx, __shfl_xor(mx, 16));
        mx = fmaxf(mx, __shfl_xor(mx, 32));

        float nm = m_i;
        if (!__all(mx <= m_i + 8.0f)) {
            nm = fmaxf(m_i, mx);
            float corr = exp2f(m_i - nm);
            l_i *= corr;
            #pragma unroll
            for (int m2 = 0; m2 < 4; ++m2) {
                acc[m2][0] *= corr; acc[m2][1] *= corr;
                acc[m2][2] *= corr; acc[m2][3] *= corr;
            }
            m_i = nm;
        }

        float ps = 0.f;
        #pragma unroll
        for (int g2 = 0; g2 < 8; ++g2) {
            bf16x4 pk;
            #pragma unroll
            for (int r = 0; r < 4; ++r) {
                float pp = exp2f(sv[g2][r] - nm);
                ps += pp;
                pk[r] = (__bf16)pp;
            }
            *(bf16x4*)&Ps[(wave * 16 + c) * VP + 16 * g2 + 4 * g] = pk;
        }
        ps += __shfl_xor(ps, 16);
        ps += __shfl_xor(ps, 32);
        l_i += ps;

        bf16x8 pf[4];
        #pragma unroll
        for (int s = 0; s < 4; ++s)
            pf[s] = *(const bf16x8*)&Ps[(wave * 16 + c) * VP + 32 * s + g * 8];
        #pragma unroll
        for (int m2 = 0; m2 < 4; ++m2) {
            #pragma unroll
            for (int s = 0; s < 4; ++s) {
                bf16x8 vf = *(const bf16x8*)&Vs[(16 * m2 + c) * VP + 32 * s + g * 8];
                acc[m2] = __builtin_amdgcn_mfma_f32_16x16x32_bf16(vf, pf[s], acc[m2], 0, 0, 0);
            }
        }
    }

    const int b = bh / TH, h = bh - b * TH;
    float inv = 1.0f / l_i;
    #pragma unroll
    for (int m2 = 0; m2 < 4; ++m2) {
        bf16x4 o;
        #pragma unroll
        for (int r = 0; r < 4; ++r)
            o[r] = (__bf16)(acc[m2][r] * inv);
        *(bf16x4*)(ctx + ((size_t)b * TT + q_glob) * TC + h * TDH + 16 * m2 + 4 * g) = o;
    }
}

// ---------------------------------------------------------------------------
extern "C" void kernel_launch(void* const* d_in, const int* in_sizes, int n_in,
                              void* d_out, int out_size, void* d_ws, size_t ws_size,
                              hipStream_t stream)
{
    const float* x    = (const float*)d_in[0];
    const float* Wq   = (const float*)d_in[1];
    const float* bq   = (const float*)d_in[2];
    const float* Wk   = (const float*)d_in[3];
    const float* bk   = (const float*)d_in[4];
    const float* Wv   = (const float*)d_in[5];
    const float* bv   = (const float*)d_in[6];
    const float* Wo   = (const float*)d_in[7];
    const float* bo   = (const float*)d_in[8];
    const float* ln1s = (const float*)d_in[9];
    const float* ln1b = (const float*)d_in[10];
    const float* W1   = (const float*)d_in[11];
    const float* b1   = (const float*)d_in[12];
    const float* W2   = (const float*)d_in[13];
    const float* b2   = (const float*)d_in[14];
    const float* ln2s = (const float*)d_in[15];
    const float* ln2b = (const float*)d_in[16];
    float* out = (float*)d_out;

    const size_t MC  = (size_t)TM * TC;       // 3,145,728 elems
    const size_t MCB = MC * 2;                // bytes of one bf16 [TM,TC]
    const size_t WSZ = (size_t)TC * TC;
    const size_t W12 = (size_t)TC * TI;

    char* W = (char*)d_ws;
    __bf16* qkvb  = (__bf16*)W;
    __bf16* x_bf  = (__bf16*)(W + 3 * MCB);
    float*  tmp1  = (float*)W;
    __bf16* u_bf  = (__bf16*)W;
    float*  h_f32 = (float*)(W + 4 * MCB);
    __bf16* ctxh  = (__bf16*)(W + 6 * MCB);
    __bf16* wts   = (__bf16*)(W + 7 * MCB);
    __bf16* WqkvT = wts;
    __bf16* WoT   = WqkvT + 3 * WSZ;
    __bf16* W1T   = WoT + WSZ;
    __bf16* W2T   = W1T + W12;

    prep_kernel<<<dim3(1536 + 6912), dim3(256), 0, stream>>>(
        x, Wq, Wk, Wv, Wo, W1, W2, x_bf, WqkvT, WoT, W1T, W2T);

    // QKV: 128x128 tiles, 512 thr / 8 waves, BK=32, grid 6x32x3 = 576 blocks
    gemm_mfma<128, 128, 64, 32, 512, 32><<<dim3(TC / 128, TM / 128, 3), dim3(512), 0, stream>>>(
        x_bf, WqkvT, bq, bk, bv, nullptr, nullptr, qkvb, TC, TC, WSZ, MC, 0);

    attn_mfma<<<dim3(TT / 64, TB * TH), dim3(256), 0, stream>>>(
        qkvb, qkvb + MC, qkvb + 2 * MC, ctxh);

    // out-proj + residual(x): 64x64 tiles, BK=64 (12 iters), grid 12x64 = 768
    gemm_mfma<64, 64, 32, 32, 256, 64><<<dim3(TC / 64, TM / 64, 1), dim3(256), 0, stream>>>(
        ctxh, WoT, bo, nullptr, nullptr, x, tmp1, nullptr, TC, TC, 0, 0, 1);

    ln_kernel<<<dim3(TM), dim3(256), 0, stream>>>(tmp1, ln1s, ln1b, h_f32, ctxh);

    // MLP1 + gelu: 128x128 tiles, 512 thr / 8 waves, BK=32, grid 24x32 = 768
    gemm_mfma<128, 128, 64, 32, 512, 32><<<dim3(TI / 128, TM / 128, 1), dim3(512), 0, stream>>>(
        ctxh, W1T, b1, nullptr, nullptr, nullptr, nullptr, u_bf, TI, TC, 0, 0, 2);

    // MLP2 + residual(h): 64x64 tiles, BK=64 (48 iters), grid 12x64 = 768
    gemm_mfma<64, 64, 32, 32, 256, 64><<<dim3(TC / 64, TM / 64, 1), dim3(256), 0, stream>>>(
        u_bf, W2T, b2, nullptr, nullptr, h_f32, out, nullptr, TC, TI, 0, 0, 1);

    ln_kernel<<<dim3(TM), dim3(256), 0, stream>>>(out, ln2s, ln2b, out, nullptr);
}

// Round 15
// 298.285 us; speedup vs baseline: 1.0954x; 1.0027x over previous
//
#include <hip/hip_runtime.h>
#include <math.h>

#define TB  2
#define TT  2048
#define TC  768
#define TH  12
#define TDH 64
#define TI  3072
#define TM  (TB*TT)   // 4096 rows

typedef __attribute__((ext_vector_type(8))) __bf16 bf16x8;
typedef __attribute__((ext_vector_type(4))) __bf16 bf16x4;
typedef __attribute__((ext_vector_type(4))) float  f32x4;

// gelu(x) = 0.5x(1+tanh(0.79788456*(x+0.044715x^3))) = x*sigmoid(2y)
//         = x / (1 + exp2(-2.30220829*(x+0.044715x^3)))   [exact identity]
__device__ __forceinline__ float gelu_tanh(float x) {
    float u = x + 0.044715f * x * x * x;
    return x / (1.0f + exp2f(-2.30220829f * u));
}

// async global->LDS, 16B per lane (wave-uniform LDS base, lane l -> base+l*16)
__device__ __forceinline__ void gld_lds16(const void* g, void* l) {
    __builtin_amdgcn_global_load_lds(
        (const __attribute__((address_space(1))) unsigned int*)g,
        (__attribute__((address_space(3))) unsigned int*)l,
        16, 0, 0);
}

template<int N>
__device__ __forceinline__ void vmcnt_wait() {
    if constexpr (N == 0)      asm volatile("s_waitcnt vmcnt(0)" ::: "memory");
    else if constexpr (N == 2) asm volatile("s_waitcnt vmcnt(2)" ::: "memory");
    else if constexpr (N == 3) asm volatile("s_waitcnt vmcnt(3)" ::: "memory");
    else if constexpr (N == 4) asm volatile("s_waitcnt vmcnt(4)" ::: "memory");
    else if constexpr (N == 6) asm volatile("s_waitcnt vmcnt(6)" ::: "memory");
    else if constexpr (N == 8) asm volatile("s_waitcnt vmcnt(8)" ::: "memory");
    else static_assert(N == 0, "unsupported vmcnt");
}

// ---------------------------------------------------------------------------
// bf16 MFMA GEMM: counted-vmcnt prefetch, templated threads + BK + NBUF.
// Round 15: ALL GEMMs -> BK=64, NBUF=2 (distance-1). Rationale (2x-validated
// fixed-cost theory): at BK=64 the compute phase doubles, so distance-1's
// latency window (1 x 16-MFMA phase) ~= old distance-2's (2 x 8-MFMA), while
// barriers per K-element halve again for QKV/MLP1 (48 -> 24). Dropping the
// 3rd buffer RAISES residency: outproj/MLP2 32KB -> 5 blocks/CU (whole
// 768-block grid co-resident, 20 waves/CU); QKV/MLP1 64KB -> 2 blocks/CU x
// 8 waves = 16 waves/CU (~= current 2.25 avg).
// All instantiations: S=4 -> waits are vmcnt(4)/vmcnt(0) only.
// XOR swizzle (audited): store phys chunk (tid%CH) holds global chunk
// (tid%CH)^(srow&7), pass-invariant (RP%8==0); read koff =
// ((kk*4+(lane>>4))^(lane&7))*8; rows hit satisfy row&7 == lane&7.
// WAR: stage at iter-it top overwrites buffer read at it-1; barrier #2 of
// it-1 orders all reads before any wave's next stage.
// ---------------------------------------------------------------------------
template<int BM_, int BN_, int WM_, int WN_, int THREADS_, int BK_, int NBUF_>
__global__ __launch_bounds__(THREADS_)
void gemm_mfma(const __bf16* __restrict__ A, const __bf16* __restrict__ Bt,
               const float* __restrict__ b0, const float* __restrict__ b1,
               const float* __restrict__ b2, const float* __restrict__ resid,
               float* __restrict__ outf, __bf16* __restrict__ outb,
               int N, int K, size_t wt_stride, size_t out_stride, int ep)
{
    constexpr int WAVES_N = BN_ / WN_;
    constexpr int TMt = WM_ / 16, TNt = WN_ / 16;
    constexpr int KSTEPS = BK_ / 32;                // MFMA k-steps per tile
    constexpr int CH   = BK_ * 2 / 16;              // 16B chunks per row (4|8)
    constexpr int RP   = THREADS_ / CH;             // staging rows per pass
    constexpr int AISS = BM_ / RP, BISS = BN_ / RP;
    constexpr int S    = AISS + BISS;               // gld_lds per thread/stage
    constexpr int PASS = THREADS_ * 16;             // bytes per staging pass
    constexpr int TILE = (BM_ + BN_) * BK_;         // elems per buffer
    constexpr int D    = NBUF_ - 1;                 // prefetch distance
    static_assert(AISS >= 1 && BISS >= 1, "tile too small for thread count");
    static_assert(NBUF_ == 2 || NBUF_ == 3, "NBUF 2 or 3");
    __shared__ __align__(16) __bf16 lds[NBUF_ * TILE];

    const int tid  = threadIdx.x;
    const int wave = tid >> 6, lane = tid & 63;
    const int wm = wave / WAVES_N, wn = wave % WAVES_N;
    const int m0 = blockIdx.y * BM_, n0 = blockIdx.x * BN_;
    const int z  = blockIdx.z;

    const __bf16* Bz = Bt + (size_t)z * wt_stride;
    const size_t Kb = (size_t)K * 2;
    const char* Ag = (const char*)A + (size_t)m0 * Kb;
    const char* Bg = (const char*)Bz + (size_t)n0 * Kb;
    const int srow = tid / CH;
    const int sswz = (BK_ == 32) ? ((srow >> 2) & 3) : (srow & 7);   // pass-invariant
    const int scol = ((tid & (CH - 1)) ^ sswz) * 16;                 // global src chunk
    const int wbase = wave * 1024;

    f32x4 acc[TMt][TNt];
    #pragma unroll
    for (int i = 0; i < TMt; ++i)
        #pragma unroll
        for (int j = 0; j < TNt; ++j)
            acc[i][j] = (f32x4){0.f, 0.f, 0.f, 0.f};

    const int arow = wm * WM_ + (lane & 15);
    const int brow = wn * WN_ + (lane & 15);
    const int swzr = (BK_ == 32) ? ((lane >> 2) & 3) : (lane & 7);   // row-derived

    const int nIter = K / BK_;

    auto stage = [&](char* base, int k0b) {
        #pragma unroll
        for (int s = 0; s < AISS; ++s)
            gld_lds16(Ag + (size_t)(srow + RP * s) * Kb + k0b + scol,
                      base + s * PASS + wbase);
        char* bbase = base + BM_ * BK_ * 2;
        #pragma unroll
        for (int s = 0; s < BISS; ++s)
            gld_lds16(Bg + (size_t)(srow + RP * s) * Kb + k0b + scol,
                      bbase + s * PASS + wbase);
    };

    char* P0 = (char*)lds;
    char* P1 = P0 + (size_t)TILE * 2;
    char* P2 = (NBUF_ == 3) ? (P1 + (size_t)TILE * 2) : P0;   // unused if NBUF==2

    stage(P0, 0);
    if constexpr (NBUF_ == 3) { if (nIter > 1) stage(P1, BK_ * 2); }
    __builtin_amdgcn_sched_barrier(0);   // pin prologue DMA issue order
    char* cur = P0; char* n1 = P1; char* n2 = P2;

    for (int it = 0; it < nIter; ++it) {
        if (it + D < nIter)
            stage((NBUF_ == 3) ? n2 : n1, (it + D) * (BK_ * 2));
        __builtin_amdgcn_sched_barrier(0);       // DMA issued before the wait
        const int rem = nIter - 1 - it;          // stages in flight beyond it
        const int w = rem < D ? rem : D;
        if (w == 2)      vmcnt_wait<2 * S>();
        else if (w == 1) vmcnt_wait<S>();
        else             vmcnt_wait<0>();
        __builtin_amdgcn_s_barrier();            // barrier #1: tile-it ready
        __builtin_amdgcn_sched_barrier(0);

        const __bf16* As = (const __bf16*)cur;
        const __bf16* Bs = As + BM_ * BK_;
        #pragma unroll
        for (int kk = 0; kk < KSTEPS; ++kk) {
            const int koff = (((kk << 2) + (lane >> 4)) ^ swzr) * 8;
            bf16x8 af[TMt], bfr[TNt];
            #pragma unroll
            for (int ti = 0; ti < TMt; ++ti)
                af[ti] = *(const bf16x8*)&As[(arow + ti * 16) * BK_ + koff];
            #pragma unroll
            for (int tj = 0; tj < TNt; ++tj)
                bfr[tj] = *(const bf16x8*)&Bs[(brow + tj * 16) * BK_ + koff];
            #pragma unroll
            for (int ti = 0; ti < TMt; ++ti)
                #pragma unroll
                for (int tj = 0; tj < TNt; ++tj)
                    acc[ti][tj] = __builtin_amdgcn_mfma_f32_16x16x32_bf16(
                        af[ti], bfr[tj], acc[ti][tj], 0, 0, 0);
        }

        __builtin_amdgcn_sched_barrier(0);
        __builtin_amdgcn_s_barrier();            // barrier #2: reads of cur done
        if constexpr (NBUF_ == 3) {
            char* t = cur; cur = n1; n1 = n2; n2 = t;
        } else {
            char* t = cur; cur = n1; n1 = t;
        }
    }

    // C/D: col = lane&15, row = (lane>>4)*4 + r
    const int lrow = m0 + wm * WM_ + ((lane >> 4) << 2);
    const int lcol = n0 + wn * WN_ + (lane & 15);

    if (ep == 0) {
        const float* bias = (z == 0) ? b0 : (z == 1) ? b1 : b2;
        __bf16* outz = outb + (size_t)z * out_stride;
        if (z < 2) {
            #pragma unroll
            for (int tj = 0; tj < TNt; ++tj) {
                int n = lcol + tj * 16;
                float bj = bias[n];
                int h = n >> 6, d = n & 63;
                #pragma unroll
                for (int ti = 0; ti < TMt; ++ti)
                    #pragma unroll
                    for (int r = 0; r < 4; ++r) {
                        int m = lrow + ti * 16 + r;
                        int b = m >> 11, t = m & (TT - 1);
                        outz[((size_t)(b * TH + h) * TT + t) * TDH + d] =
                            (__bf16)(acc[ti][tj][r] + bj);
                    }
            }
        } else {
            #pragma unroll
            for (int tj = 0; tj < TNt; ++tj) {
                int n = lcol + tj * 16;
                float bj = bias[n];
                int h = n >> 6, d = n & 63;
                #pragma unroll
                for (int ti = 0; ti < TMt; ++ti) {
                    int m = lrow + ti * 16;
                    int b = m >> 11, t0 = m & (TT - 1);
                    bf16x4 pk;
                    #pragma unroll
                    for (int r = 0; r < 4; ++r)
                        pk[r] = (__bf16)(acc[ti][tj][r] + bj);
                    *(bf16x4*)(outz + ((size_t)(b * TH + h) * TDH + d) * TT + t0) = pk;
                }
            }
        }
    } else if (ep == 1) {
        #pragma unroll
        for (int tj = 0; tj < TNt; ++tj) {
            int n = lcol + tj * 16;
            float bj = b0[n];
            #pragma unroll
            for (int ti = 0; ti < TMt; ++ti)
                #pragma unroll
                for (int r = 0; r < 4; ++r) {
                    int m = lrow + ti * 16 + r;
                    outf[(size_t)m * N + n] =
                        acc[ti][tj][r] + bj + resid[(size_t)m * N + n];
                }
        }
    } else {
        #pragma unroll
        for (int tj = 0; tj < TNt; ++tj) {
            int n = lcol + tj * 16;
            float bj = b0[n];
            #pragma unroll
            for (int ti = 0; ti < TMt; ++ti)
                #pragma unroll
                for (int r = 0; r < 4; ++r) {
                    int m = lrow + ti * 16 + r;
                    outb[(size_t)m * N + n] = (__bf16)gelu_tanh(acc[ti][tj][r] + bj);
                }
        }
    }
}

// ---------------------------------------------------------------------------
// Fused prep: x fp32->bf16 (blocks [0,1536)) + 6 weight transposes to bf16
// ---------------------------------------------------------------------------
__global__ __launch_bounds__(256)
void prep_kernel(const float* __restrict__ x,
                 const float* __restrict__ Wq, const float* __restrict__ Wk,
                 const float* __restrict__ Wv, const float* __restrict__ Wo,
                 const float* __restrict__ W1, const float* __restrict__ W2,
                 __bf16* __restrict__ x_bf, __bf16* __restrict__ WqkvT,
                 __bf16* __restrict__ WoT, __bf16* __restrict__ W1T,
                 __bf16* __restrict__ W2T)
{
    const size_t WSZ = (size_t)TC * TC;
    int bid = blockIdx.x;
    if (bid < 1536) {                        // x conversion: 1536*256*8 = MC
        int i = (bid * 256 + threadIdx.x) * 8;
        float4 a = *(const float4*)(x + i);
        float4 b = *(const float4*)(x + i + 4);
        bf16x8 v;
        v[0] = (__bf16)a.x; v[1] = (__bf16)a.y; v[2] = (__bf16)a.z; v[3] = (__bf16)a.w;
        v[4] = (__bf16)b.x; v[5] = (__bf16)b.y; v[6] = (__bf16)b.z; v[7] = (__bf16)b.w;
        *(bf16x8*)(x_bf + i) = v;
        return;
    }
    bid -= 1536;
    const float* src; __bf16* dst; int K, N, tloc;
    if (bid < 2304) {            // Wq/Wk/Wv/Wo: 576 tiles each
        int w = bid / 576; tloc = bid - w * 576;
        K = TC; N = TC;
        src = (w == 0) ? Wq : (w == 1) ? Wk : (w == 2) ? Wv : Wo;
        dst = (w < 3) ? (WqkvT + (size_t)w * WSZ) : WoT;
    } else if (bid < 4608) {     // W1 [768,3072]
        tloc = bid - 2304; K = TC; N = TI; src = W1; dst = W1T;
    } else {                     // W2 [3072,768]
        tloc = bid - 4608; K = TI; N = TC; src = W2; dst = W2T;
    }
    int tiles_x = N >> 5;
    int n0 = (tloc % tiles_x) * 32, k0 = (tloc / tiles_x) * 32;

    __shared__ float tile[32][33];
    const int tx = threadIdx.x & 31, ty = threadIdx.x >> 5;
    #pragma unroll
    for (int i = 0; i < 32; i += 8)
        tile[ty + i][tx] = src[(size_t)(k0 + ty + i) * N + n0 + tx];
    __syncthreads();
    #pragma unroll
    for (int i = 0; i < 32; i += 8)
        dst[(size_t)(n0 + ty + i) * K + k0 + tx] = (__bf16)tile[tx][ty + i];
}

// ---------------------------------------------------------------------------
// LayerNorm (ddof=1, EPS=1e-4), optional bf16 copy
// ---------------------------------------------------------------------------
__global__ __launch_bounds__(256)
void ln_kernel(const float* __restrict__ in, const float* __restrict__ gs,
               const float* __restrict__ gb, float* __restrict__ out,
               __bf16* __restrict__ out_bf)
{
    const int row = blockIdx.x, tid = threadIdx.x;
    const float* r = in + (size_t)row * TC;
    float x0 = r[tid], x1 = r[tid + 256], x2 = r[tid + 512];
    float s = x0 + x1 + x2;
    float q = x0 * x0 + x1 * x1 + x2 * x2;
    #pragma unroll
    for (int off = 32; off > 0; off >>= 1) {
        s += __shfl_down(s, off);
        q += __shfl_down(q, off);
    }
    __shared__ float partial[8];
    __shared__ float stats[2];
    int wid = tid >> 6, lane = tid & 63;
    if (lane == 0) { partial[wid] = s; partial[wid + 4] = q; }
    __syncthreads();
    if (tid == 0) {
        float S = partial[0] + partial[1] + partial[2] + partial[3];
        float Q = partial[4] + partial[5] + partial[6] + partial[7];
        float mean = S * (1.0f / (float)TC);
        float var = (Q - (float)TC * mean * mean) * (1.0f / (float)(TC - 1));
        stats[0] = mean;
        stats[1] = rsqrtf(var + 1e-4f);
    }
    __syncthreads();
    float mean = stats[0], rstd = stats[1];
    float* w = out + (size_t)row * TC;
    float y0 = gs[tid]       * ((x0 - mean) * rstd) + gb[tid];
    float y1 = gs[tid + 256] * ((x1 - mean) * rstd) + gb[tid + 256];
    float y2 = gs[tid + 512] * ((x2 - mean) * rstd) + gb[tid + 512];
    w[tid] = y0; w[tid + 256] = y1; w[tid + 512] = y2;
    if (out_bf) {
        __bf16* wb = out_bf + (size_t)row * TC;
        wb[tid] = (__bf16)y0; wb[tid + 256] = (__bf16)y1; wb[tid + 512] = (__bf16)y2;
    }
}

// ---------------------------------------------------------------------------
// MFMA flash attention v4 (round-6/9 version, best measured 62.5 us):
// 768-block snake, 3 blocks/CU, KVBLK=128 per iter, defer-max, exp2 softmax.
// ---------------------------------------------------------------------------
#define AP 72
#define VP 136
#define ATT_SCALE 0.18033688011112042f   /* 0.125 * log2(e) */

__global__ __launch_bounds__(256)
void attn_mfma(const __bf16* __restrict__ Q, const __bf16* __restrict__ K,
               const __bf16* __restrict__ Vt, __bf16* __restrict__ ctx)
{
    __shared__ __align__(16) __bf16 Ks[128 * AP];
    __shared__ __align__(16) __bf16 Vs[64 * VP];
    __shared__ __align__(16) __bf16 Ps[64 * VP];

    const int tid  = threadIdx.x;
    const int wave = tid >> 6, lane = tid & 63;
    const int c = lane & 15, g = lane >> 4;
    const int bh = blockIdx.y;
    const int qi = blockIdx.x;
    const int qt = (qi & 1) ? (31 - (qi >> 1)) : (qi >> 1);
    const int q_glob = qt * 64 + wave * 16 + c;

    const __bf16* Qb = Q  + (size_t)bh * TT * TDH;
    const __bf16* Kb = K  + (size_t)bh * TT * TDH;
    const __bf16* Vb = Vt + (size_t)bh * TDH * TT;

    bf16x8 qf0 = *(const bf16x8*)(Qb + (size_t)q_glob * TDH + g * 8);
    bf16x8 qf1 = *(const bf16x8*)(Qb + (size_t)q_glob * TDH + 32 + g * 8);

    const int krow = tid >> 3, kcol = (tid & 7) * 8;
    const int vrow = tid >> 4, vcol = (tid & 15) * 8;

    float m_i = -1e30f, l_i = 0.0f;
    f32x4 acc[4];
    #pragma unroll
    for (int m2 = 0; m2 < 4; ++m2) acc[m2] = (f32x4){0.f, 0.f, 0.f, 0.f};

    const int pmax = qt >> 1;
    for (int p = 0; p <= pmax; ++p) {
        const int kb = p * 128;
        bf16x8 kv[4], vv[4];
        #pragma unroll
        for (int s = 0; s < 4; ++s) {
            kv[s] = *(const bf16x8*)(Kb + (size_t)(kb + krow + 32 * s) * TDH + kcol);
            vv[s] = *(const bf16x8*)(Vb + (size_t)(vrow + 16 * s) * TT + kb + vcol);
        }
        __syncthreads();
        #pragma unroll
        for (int s = 0; s < 4; ++s) {
            *(bf16x8*)&Ks[(krow + 32 * s) * AP + kcol] = kv[s];
            *(bf16x8*)&Vs[(vrow + 16 * s) * VP + vcol] = vv[s];
        }
        __syncthreads();

        f32x4 st[8];
        #pragma unroll
        for (int g2 = 0; g2 < 8; ++g2) {
            bf16x8 af0 = *(const bf16x8*)&Ks[(16 * g2 + c) * AP + g * 8];
            bf16x8 af1 = *(const bf16x8*)&Ks[(16 * g2 + c) * AP + 32 + g * 8];
            f32x4 z = (f32x4){0.f, 0.f, 0.f, 0.f};
            z = __builtin_amdgcn_mfma_f32_16x16x32_bf16(af0, qf0, z, 0, 0, 0);
            z = __builtin_amdgcn_mfma_f32_16x16x32_bf16(af1, qf1, z, 0, 0, 0);
            st[g2] = z;
        }

        float sv[8][4];
        float mx = -1e30f;
        if (p == pmax) {            // diagonal pair: causal mask
            #pragma unroll
            for (int g2 = 0; g2 < 8; ++g2)
                #pragma unroll
                for (int r = 0; r < 4; ++r) {
                    int kcol2 = kb + 16 * g2 + 4 * g + r;
                    float v = (kcol2 > q_glob) ? -1e30f : st[g2][r] * ATT_SCALE;
                    sv[g2][r] = v;
                    mx = fmaxf(mx, v);
                }
        } else {
            #pragma unroll
            for (int g2 = 0; g2 < 8; ++g2)
                #pragma unroll
                for (int r = 0; r < 4; ++r) {
                    float v = st[g2][r] * ATT_SCALE;
                    sv[g2][r] = v;
                    mx = fmaxf(mx, v);
                }
        }
        mx = fmaxf(mx, __shfl_xor(mx, 16));
        mx = fmaxf(mx, __shfl_xor(mx, 32));

        float nm = m_i;
        if (!__all(mx <= m_i + 8.0f)) {
            nm = fmaxf(m_i, mx);
            float corr = exp2f(m_i - nm);
            l_i *= corr;
            #pragma unroll
            for (int m2 = 0; m2 < 4; ++m2) {
                acc[m2][0] *= corr; acc[m2][1] *= corr;
                acc[m2][2] *= corr; acc[m2][3] *= corr;
            }
            m_i = nm;
        }

        float ps = 0.f;
        #pragma unroll
        for (int g2 = 0; g2 < 8; ++g2) {
            bf16x4 pk;
            #pragma unroll
            for (int r = 0; r < 4; ++r) {
                float pp = exp2f(sv[g2][r] - nm);
                ps += pp;
                pk[r] = (__bf16)pp;
            }
            *(bf16x4*)&Ps[(wave * 16 + c) * VP + 16 * g2 + 4 * g] = pk;
        }
        ps += __shfl_xor(ps, 16);
        ps += __shfl_xor(ps, 32);
        l_i += ps;

        bf16x8 pf[4];
        #pragma unroll
        for (int s = 0; s < 4; ++s)
            pf[s] = *(const bf16x8*)&Ps[(wave * 16 + c) * VP + 32 * s + g * 8];
        #pragma unroll
        for (int m2 = 0; m2 < 4; ++m2) {
            #pragma unroll
            for (int s = 0; s < 4; ++s) {
                bf16x8 vf = *(const bf16x8*)&Vs[(16 * m2 + c) * VP + 32 * s + g * 8];
                acc[m2] = __builtin_amdgcn_mfma_f32_16x16x32_bf16(vf, pf[s], acc[m2], 0, 0, 0);
            }
        }
    }

    const int b = bh / TH, h = bh - b * TH;
    float inv = 1.0f / l_i;
    #pragma unroll
    for (int m2 = 0; m2 < 4; ++m2) {
        bf16x4 o;
        #pragma unroll
        for (int r = 0; r < 4; ++r)
            o[r] = (__bf16)(acc[m2][r] * inv);
        *(bf16x4*)(ctx + ((size_t)b * TT + q_glob) * TC + h * TDH + 16 * m2 + 4 * g) = o;
    }
}

// ---------------------------------------------------------------------------
extern "C" void kernel_launch(void* const* d_in, const int* in_sizes, int n_in,
                              void* d_out, int out_size, void* d_ws, size_t ws_size,
                              hipStream_t stream)
{
    const float* x    = (const float*)d_in[0];
    const float* Wq   = (const float*)d_in[1];
    const float* bq   = (const float*)d_in[2];
    const float* Wk   = (const float*)d_in[3];
    const float* bk   = (const float*)d_in[4];
    const float* Wv   = (const float*)d_in[5];
    const float* bv   = (const float*)d_in[6];
    const float* Wo   = (const float*)d_in[7];
    const float* bo   = (const float*)d_in[8];
    const float* ln1s = (const float*)d_in[9];
    const float* ln1b = (const float*)d_in[10];
    const float* W1   = (const float*)d_in[11];
    const float* b1   = (const float*)d_in[12];
    const float* W2   = (const float*)d_in[13];
    const float* b2   = (const float*)d_in[14];
    const float* ln2s = (const float*)d_in[15];
    const float* ln2b = (const float*)d_in[16];
    float* out = (float*)d_out;

    const size_t MC  = (size_t)TM * TC;       // 3,145,728 elems
    const size_t MCB = MC * 2;                // bytes of one bf16 [TM,TC]
    const size_t WSZ = (size_t)TC * TC;
    const size_t W12 = (size_t)TC * TI;

    char* W = (char*)d_ws;
    __bf16* qkvb  = (__bf16*)W;
    __bf16* x_bf  = (__bf16*)(W + 3 * MCB);
    float*  tmp1  = (float*)W;
    __bf16* u_bf  = (__bf16*)W;
    float*  h_f32 = (float*)(W + 4 * MCB);
    __bf16* ctxh  = (__bf16*)(W + 6 * MCB);
    __bf16* wts   = (__bf16*)(W + 7 * MCB);
    __bf16* WqkvT = wts;
    __bf16* WoT   = WqkvT + 3 * WSZ;
    __bf16* W1T   = WoT + WSZ;
    __bf16* W2T   = W1T + W12;

    prep_kernel<<<dim3(1536 + 6912), dim3(256), 0, stream>>>(
        x, Wq, Wk, Wv, Wo, W1, W2, x_bf, WqkvT, WoT, W1T, W2T);

    // QKV: 128x128, 512 thr / 8 waves, BK=64, NBUF=2 (64KB -> 2 blk/CU)
    gemm_mfma<128, 128, 64, 32, 512, 64, 2><<<dim3(TC / 128, TM / 128, 3), dim3(512), 0, stream>>>(
        x_bf, WqkvT, bq, bk, bv, nullptr, nullptr, qkvb, TC, TC, WSZ, MC, 0);

    attn_mfma<<<dim3(TT / 64, TB * TH), dim3(256), 0, stream>>>(
        qkvb, qkvb + MC, qkvb + 2 * MC, ctxh);

    // out-proj + residual(x): 64x64, BK=64, NBUF=2 (32KB -> 5 blk/CU)
    gemm_mfma<64, 64, 32, 32, 256, 64, 2><<<dim3(TC / 64, TM / 64, 1), dim3(256), 0, stream>>>(
        ctxh, WoT, bo, nullptr, nullptr, x, tmp1, nullptr, TC, TC, 0, 0, 1);

    ln_kernel<<<dim3(TM), dim3(256), 0, stream>>>(tmp1, ln1s, ln1b, h_f32, ctxh);

    // MLP1 + gelu: 128x128, 512 thr / 8 waves, BK=64, NBUF=2
    gemm_mfma<128, 128, 64, 32, 512, 64, 2><<<dim3(TI / 128, TM / 128, 1), dim3(512), 0, stream>>>(
        ctxh, W1T, b1, nullptr, nullptr, nullptr, nullptr, u_bf, TI, TC, 0, 0, 2);

    // MLP2 + residual(h): 64x64, BK=64, NBUF=2 (5 blk/CU, grid fully resident)
    gemm_mfma<64, 64, 32, 32, 256, 64, 2><<<dim3(TC / 64, TM / 64, 1), dim3(256), 0, stream>>>(
        u_bf, W2T, b2, nullptr, nullptr, h_f32, out, nullptr, TC, TI, 0, 0, 1);

    ln_kernel<<<dim3(TM), dim3(256), 0, stream>>>(out, ln2s, ln2b, out, nullptr);
}